// Round 16
// baseline (900.351 us; speedup 1.0000x reference)
//
#include <hip/hip_runtime.h>
#include <hip/hip_bf16.h>

#define EPSN 1e-5f

typedef __bf16 bf16x8 __attribute__((ext_vector_type(8)));
typedef float f32x4 __attribute__((ext_vector_type(4)));

template <int V> struct ICst { static constexpr int value = V; };

// ---- order-preserving float<->uint encoding for max pooling ----
// enc sentinel 0u decodes to NaN -> poisons only empty-cell rows, masked at write.
__device__ __forceinline__ unsigned encf(float f) {
  unsigned u = __float_as_uint(f);
  return (u & 0x80000000u) ? ~u : (u | 0x80000000u);
}
__device__ __forceinline__ float decf(unsigned u) {
  return (u & 0x80000000u) ? __uint_as_float(u ^ 0x80000000u) : __uint_as_float(~u);
}

// ---- column stats (sum, sumsq) of the raw 3-feature input ----
__global__ __launch_bounds__(256) void stats_feats(const float* __restrict__ pt, int n,
                                                   float* __restrict__ sums) {
  float a0 = 0, a1 = 0, a2 = 0, q0 = 0, q1 = 0, q2 = 0;
  for (int p = blockIdx.x * 256 + threadIdx.x; p < n; p += gridDim.x * 256) {
    float v0 = pt[3 * p], v1 = pt[3 * p + 1], v2 = pt[3 * p + 2];
    a0 += v0; a1 += v1; a2 += v2;
    q0 += v0 * v0; q1 += v1 * v1; q2 += v2 * v2;
  }
  __shared__ float red[4][6];
  float vals[6] = {a0, a1, a2, q0, q1, q2};
  int lane = threadIdx.x & 63, wv = threadIdx.x >> 6;
#pragma unroll
  for (int k = 0; k < 6; k++) {
    float v = vals[k];
#pragma unroll
    for (int o = 32; o; o >>= 1) v += __shfl_down(v, o, 64);
    if (lane == 0) red[wv][k] = v;
  }
  __syncthreads();
  if (threadIdx.x < 6) {
    float v = red[0][threadIdx.x] + red[1][threadIdx.x] + red[2][threadIdx.x] + red[3][threadIdx.x];
    atomicAdd(&sums[threadIdx.x], v);
  }
}

// ---- fold BN (train-mode batch stats) + affine into per-column scale/shift ----
__global__ void bn_prep(const float* __restrict__ sums, int C, float invN,
                        const float* __restrict__ g, const float* __restrict__ be,
                        float* __restrict__ sc, float* __restrict__ sh) {
  int c = threadIdx.x;
  if (c < C) {
    float m = sums[c] * invN;
    float v = fmaxf(sums[C + c] * invN - m * m, 0.f);
    float s = g[c] * rsqrtf(v + EPSN);
    sc[c] = s;
    sh[c] = be[c] - m * s;
  }
}

// ---- fused weight conversions: fp32 W[K][C] -> bf16 Wt[C][K] for all 4 weights ----
__global__ __launch_bounds__(256) void wconv4(
    const float* __restrict__ W2, const float* __restrict__ W3,
    const float* __restrict__ W4, const float* __restrict__ Wc,
    __hip_bfloat16* __restrict__ Wt2, __hip_bfloat16* __restrict__ Wt3,
    __hip_bfloat16* __restrict__ Wt4, __hip_bfloat16* __restrict__ WcT) {
  int idx = blockIdx.x * 256 + threadIdx.x;
  const float* W; __hip_bfloat16* Wt; int K, C, l;
  if (idx < 8192)        { W = W2; Wt = Wt2; K = 64;  C = 128; l = idx; }
  else if (idx < 40960)  { W = W3; Wt = Wt3; K = 128; C = 256; l = idx - 8192; }
  else if (idx < 172032) { W = W4; Wt = Wt4; K = 256; C = 512; l = idx - 40960; }
  else if (idx < 188416) { W = Wc; Wt = WcT; K = 512; C = 32;  l = idx - 172032; }
  else return;
  int k = l / C, c = l - k * C;
  Wt[(size_t)c * K + k] = __float2bfloat16(W[l]);
}

// ---- stage 1 fused: Y1 = BN(feats)@W1 + b1, column stats inline ----
__global__ __launch_bounds__(256) void gemm1_stats(const float* __restrict__ pt,
                                                   const float* __restrict__ W,
                                                   const float* __restrict__ bias,
                                                   const float* __restrict__ scsh,
                                                   __hip_bfloat16* __restrict__ Y,
                                                   int n, float* __restrict__ sums) {
  const int c = threadIdx.x & 63;
  const float w0 = W[c], w1 = W[64 + c], w2 = W[128 + c], bb = bias[c];
  const float s0 = scsh[0], s1 = scsh[1], s2 = scsh[2];
  const float h0 = scsh[4], h1 = scsh[5], h2 = scsh[6];
  float s = 0.f, q = 0.f;
  const int total = n * 64;
  for (int idx = blockIdx.x * 256 + threadIdx.x; idx < total; idx += gridDim.x * 256) {
    int p = idx >> 6;
    float x0 = s0 * pt[3 * p]     + h0;
    float x1 = s1 * pt[3 * p + 1] + h1;
    float x2 = s2 * pt[3 * p + 2] + h2;
    float y = bb + x0 * w0 + x1 * w1 + x2 * w2;
    Y[idx] = __float2bfloat16(y);
    s += y; q += y * y;
  }
  __shared__ float sred[4][64], qred[4][64];
  int wv = threadIdx.x >> 6;
  sred[wv][c] = s; qred[wv][c] = q;
  __syncthreads();
  if (threadIdx.x < 64) {
    float S = sred[0][c] + sred[1][c] + sred[2][c] + sred[3][c];
    float Q = qred[0][c] + qred[1][c] + qred[2][c] + qred[3][c];
    atomicAdd(&sums[c], S);
    atomicAdd(&sums[64 + c], Q);
  }
}

// ---- MFMA GEMM (stages 2/3): Yout = relu(sc*Yin+sh)@W + bias, fused column stats.
// Output staged through LDS, contiguous 64B/lane stores. Optional perm: output
// row i lands at row perm[i] (stage 3 writes Y3 in SORTED order so stage 4 reads
// are contiguous -- write-side scatter is fire-and-forget). ----
template <int K>
__global__ __launch_bounds__(256) void gemm_mfma(
    const __hip_bfloat16* __restrict__ Yin, const __hip_bfloat16* __restrict__ Wt,
    const float* __restrict__ bias, const float* __restrict__ sc, const float* __restrict__ sh,
    __hip_bfloat16* __restrict__ Yout, int C, float* __restrict__ sums, int nrows,
    const unsigned* __restrict__ perm) {
  constexpr int KS = 64, LDA = 72, LDO = 80;
  __shared__ __align__(16) __hip_bfloat16 hA[128 * LDO];
  __shared__ float sredArr[128], qredArr[128];
  const int t = threadIdx.x;
  const int lane = t & 63, wv = t >> 6;
  const int mh = (wv >> 1) * 64, nh = (wv & 1) * 64;
  const int lm = lane & 15, lq = lane >> 4;
  const int p0 = blockIdx.x * 128;
  const int cb0 = blockIdx.y * 128;

  f32x4 acc[4][4];
#pragma unroll
  for (int i = 0; i < 4; i++)
#pragma unroll
    for (int j = 0; j < 4; j++) acc[i][j] = {0.f, 0.f, 0.f, 0.f};

  for (int k0 = 0; k0 < K; k0 += KS) {
    __syncthreads();
#pragma unroll
    for (int it = 0; it < 4; it++) {
      int idx = it * 256 + t;
      int row = idx >> 3;
      int c8 = (idx & 7) * 8;
      int gp = p0 + row;
      __hip_bfloat16 h8[8];
      if (gp < nrows) {
        uint4 raw = *(const uint4*)(Yin + (size_t)gp * K + k0 + c8);
        const __hip_bfloat16* pr = (const __hip_bfloat16*)&raw;
#pragma unroll
        for (int j = 0; j < 8; j++) {
          float v = sc[k0 + c8 + j] * __bfloat162float(pr[j]) + sh[k0 + c8 + j];
          h8[j] = __float2bfloat16(fmaxf(v, 0.f));
        }
      } else {
#pragma unroll
        for (int j = 0; j < 8; j++) h8[j] = __float2bfloat16(0.f);
      }
      *(uint4*)&hA[row * LDA + c8] = *(const uint4*)h8;
    }
    __syncthreads();
#pragma unroll
    for (int kk = 0; kk < KS; kk += 32) {
      bf16x8 a[4], b[4];
#pragma unroll
      for (int i = 0; i < 4; i++)
        a[i] = *(const bf16x8*)&hA[(mh + i * 16 + lm) * LDA + kk + lq * 8];
#pragma unroll
      for (int j = 0; j < 4; j++)
        b[j] = *(const bf16x8*)(const void*)(Wt + (size_t)(cb0 + nh + j * 16 + lm) * K + k0 + kk + lq * 8);
#pragma unroll
      for (int i = 0; i < 4; i++)
#pragma unroll
        for (int j = 0; j < 4; j++)
          acc[i][j] = __builtin_amdgcn_mfma_f32_16x16x32_bf16(a[i], b[j], acc[i][j], 0, 0, 0);
    }
  }

#pragma unroll
  for (int j = 0; j < 4; j++) {
    float bb = bias[cb0 + nh + j * 16 + lm];
#pragma unroll
    for (int i = 0; i < 4; i++)
#pragma unroll
      for (int r = 0; r < 4; r++) acc[i][j][r] += bb;
  }

  __syncthreads();
  if (t < 128) { sredArr[t] = 0.f; qredArr[t] = 0.f; }
  __syncthreads();

#pragma unroll
  for (int j = 0; j < 4; j++) {
    float s = 0.f, q = 0.f;
#pragma unroll
    for (int i = 0; i < 4; i++)
#pragma unroll
      for (int r = 0; r < 4; r++) {
        int grow = p0 + mh + i * 16 + lq * 4 + r;
        if (grow < nrows) { float v = acc[i][j][r]; s += v; q += v * v; }
      }
    s += __shfl_xor(s, 16); s += __shfl_xor(s, 32);
    q += __shfl_xor(q, 16); q += __shfl_xor(q, 32);
    if (lq == 0) {
      atomicAdd(&sredArr[nh + j * 16 + lm], s);
      atomicAdd(&qredArr[nh + j * 16 + lm], q);
    }
  }

  for (int half = 0; half < 2; half++) {
    __syncthreads();
    if ((wv & 1) == half) {
#pragma unroll
      for (int j = 0; j < 4; j++)
#pragma unroll
        for (int i = 0; i < 4; i++)
#pragma unroll
          for (int r = 0; r < 4; r++)
            hA[(mh + i * 16 + lq * 4 + r) * LDO + j * 16 + lm] = __float2bfloat16(acc[i][j][r]);
    }
    __syncthreads();
    int row = t >> 1, seg = t & 1;
    int gp = p0 + row;
    if (gp < nrows) {
      size_t drow = perm ? (size_t)perm[gp] : (size_t)gp;
      const uint4* src = (const uint4*)&hA[row * LDO + seg * 32];
      uint4* dst = (uint4*)(Yout + drow * C + cb0 + half * 64 + seg * 32);
      dst[0] = src[0]; dst[1] = src[1]; dst[2] = src[2]; dst[3] = src[3];
    }
  }

  if (t < 128) {
    atomicAdd(&sums[cb0 + t], sredArr[t]);
    atomicAdd(&sums[C + cb0 + t], qredArr[t]);
  }
}

// ---- counting sort (batched over blockIdx.y) ----
__global__ __launch_bounds__(256) void hist_kernel(const int* __restrict__ gi, int perB,
                                                   unsigned* __restrict__ hist) {
  int b = blockIdx.y;
  int p = blockIdx.x * 256 + threadIdx.x;
  if (p < perB) {
    int gp = b * perB + p;
    int c = (gi[2 * gp] & 255) * 256 + (gi[2 * gp + 1] & 255);
    atomicAdd(&hist[b * 65536 + c], 1u);
  }
}
__global__ __launch_bounds__(256) void scan1(const unsigned* __restrict__ hist,
                                             unsigned* __restrict__ cursor,
                                             unsigned* __restrict__ bSums) {
  __shared__ unsigned s[256];
  int b = blockIdx.y;
  int t = threadIdx.x, i = b * 65536 + blockIdx.x * 256 + t;
  unsigned v = hist[i]; s[t] = v; __syncthreads();
  for (int off = 1; off < 256; off <<= 1) {
    unsigned x = (t >= off) ? s[t - off] : 0u; __syncthreads();
    s[t] += x; __syncthreads();
  }
  cursor[i] = s[t] - v;
  if (t == 255) bSums[b * 256 + blockIdx.x] = s[255];
}
__global__ void scan2(unsigned* __restrict__ bSums) {  // grid = 2 blocks (one per batch)
  __shared__ unsigned s[256];
  int t = threadIdx.x, i = blockIdx.x * 256 + t;
  unsigned v = bSums[i]; s[t] = v; __syncthreads();
  for (int off = 1; off < 256; off <<= 1) {
    unsigned x = (t >= off) ? s[t - off] : 0u; __syncthreads();
    s[t] += x; __syncthreads();
  }
  bSums[i] = s[t] - v;
}
// starts[b][c] = global exclusive prefix; starts[b][65536] = perB  (runs BEFORE scatter)
__global__ __launch_bounds__(256) void mk_starts(const unsigned* __restrict__ cursor,
                                                 const unsigned* __restrict__ bSums,
                                                 unsigned* __restrict__ starts, int perB) {
  int b = blockIdx.y;
  int i = blockIdx.x * 256 + threadIdx.x;
  starts[b * 65537 + i] = cursor[b * 65536 + i] + bSums[b * 256 + (i >> 8)];
  if (i == 0) starts[b * 65537 + 65536] = (unsigned)perB;
}
// scatter: cells[sorted position] = cell id; invPos[point] = global sorted row.
__global__ __launch_bounds__(256) void scatter_kernel(const int* __restrict__ gi, int perB,
                                                      unsigned* __restrict__ cursor,
                                                      const unsigned* __restrict__ bSums,
                                                      unsigned* __restrict__ cells,
                                                      unsigned* __restrict__ invPos) {
  int b = blockIdx.y;
  int p = blockIdx.x * 256 + threadIdx.x;
  if (p < perB) {
    int gp = b * perB + p;
    int c = (gi[2 * gp] & 255) * 256 + (gi[2 * gp + 1] & 255);
    unsigned pos = atomicAdd(&cursor[b * 65536 + c], 1u) + bSums[b * 256 + (c >> 8)];
    if (pos >= (unsigned)perB) pos = (unsigned)perB - 1u;  // fault insurance: never triggers
    cells[b * perB + pos] = (unsigned)c;
    invPos[gp] = (unsigned)(b * perB) + pos;
  }
}

// ---- fused stage-4 (r15 base + tail-stripe specialization): 32 exclusive cells,
// M=64, 256 thr, LDS 76.8 KB, (256,2) -- the only clean register point. Y3 sorted
// -> contiguous staging; run-merged atomics (r15: -33% atomic insts, -40us).
// NEW: rg body templated on stripe count S in {4,2,1}, selected by wave-uniform
// nlive = n - rbase (>32 -> 4, >16 -> 2, else 1). 24% of blocks have a tail rg
// with ~6 live rows; S=1 gives them 1/4 the staging chunks, 1/4 the MFMAs, 1/4
// the atomic sections at identical barrier structure. Register allocation = max
// path (S=4) = unchanged. Kill criteria: WRITE_SIZE 16 MB, VGPR ~116. ----
__global__ __launch_bounds__(256, 2) void pool_compress(
    const __hip_bfloat16* __restrict__ Y3, const __hip_bfloat16* __restrict__ Wt4,
    const float* __restrict__ b4, const float* __restrict__ sc, const float* __restrict__ sh,
    const __hip_bfloat16* __restrict__ WcT, const float* __restrict__ bc,
    const unsigned* __restrict__ sortedCell, const unsigned* __restrict__ startsAll,
    float* __restrict__ comp, int perB) {
  constexpr int K = 256, KS = 64, LDA = 72, MLW = 516;
  __shared__ __align__(16) __hip_bfloat16 hA[64 * LDA];   // 9.2 KB
  __shared__ __align__(16) unsigned maxLds[32 * MLW];     // 66.0 KB
  __shared__ unsigned char slotRow[256];
  const int t = threadIdx.x;
  const int lane = t & 63, wv = t >> 6;  // wave grid 1M x 4N: wave wv owns cols [wv*128, +128)
  const int lm = lane & 15, lq = lane >> 4;
  const int batch = blockIdx.y;
  const unsigned* starts = startsAll + batch * 65537;
  const int c0 = blockIdx.x * 32;
  const int r0 = (int)starts[c0];
  int n = (int)starts[c0 + 32] - r0;
  if (n > 256) n = 256;  // safety clamp (32 cells, ~59 pts avg: never hit)
  if (n < 0) n = 0;
  const int nrg = (n + 63) >> 6;
  const size_t rowBase = (size_t)batch * perB + r0;

  for (int i = t; i < n; i += 256)
    slotRow[i] = (unsigned char)((sortedCell[batch * perB + r0 + i] - c0) & 31);
  {
    const uint4 z4 = {0u, 0u, 0u, 0u};
    for (int i = t * 4; i < 32 * MLW; i += 1024) *(uint4*)&maxLds[i] = z4;
  }

  // rg body: stages S*16 rows, MFMAs S stripes, run-merged segmax over S stripes.
  auto rgBody = [&](int rbase, auto SC) {
    constexpr int S = decltype(SC)::value;
    f32x4 acc[S][8];
#pragma unroll
    for (int i = 0; i < S; i++)
#pragma unroll
      for (int j = 0; j < 8; j++) acc[i][j] = {0.f, 0.f, 0.f, 0.f};
    for (int k0 = 0; k0 < K; k0 += KS) {
      __syncthreads();  // hA free (covers init/zeroing on first pass, prior reads after)
      for (int idx = t; idx < S * 128; idx += 256) {
        int row = idx >> 3;
        int c8 = (idx & 7) * 8;
        int gr = rbase + row;
        __hip_bfloat16 h8[8];
        if (gr < n) {
          uint4 raw = *(const uint4*)(Y3 + (rowBase + gr) * K + k0 + c8);
          const __hip_bfloat16* pr = (const __hip_bfloat16*)&raw;
#pragma unroll
          for (int j = 0; j < 8; j++) {
            float v = sc[k0 + c8 + j] * __bfloat162float(pr[j]) + sh[k0 + c8 + j];
            h8[j] = __float2bfloat16(fmaxf(v, 0.f));
          }
        } else {
#pragma unroll
          for (int j = 0; j < 8; j++) h8[j] = __float2bfloat16(0.f);
        }
        *(uint4*)&hA[row * LDA + c8] = *(const uint4*)h8;
      }
      __syncthreads();
#pragma unroll
      for (int kk = 0; kk < KS; kk += 32) {
        bf16x8 a[S];
#pragma unroll
        for (int i = 0; i < S; i++)
          a[i] = *(const bf16x8*)&hA[(i * 16 + lm) * LDA + kk + lq * 8];
#pragma unroll
        for (int j = 0; j < 8; j++) {
          bf16x8 b = *(const bf16x8*)(const void*)(Wt4 + (size_t)(wv * 128 + j * 16 + lm) * K + k0 + kk + lq * 8);
#pragma unroll
          for (int i = 0; i < S; i++)
            acc[i][j] = __builtin_amdgcn_mfma_f32_16x16x32_bf16(a[i], b, acc[i][j], 0, 0, 0);
        }
      }
    }
    // segmented max with run-merging (raw h4; bias folded at compress).
    // Rows of one f32x4 are consecutive -> fold same-cell neighbors in-register,
    // emit one atomic per run. Conditions uniform across j (hoisted).
#pragma unroll
    for (int i = 0; i < S; i++) {
      const int base = rbase + i * 16 + lq * 4;
      const int rl = n - base;  // rows valid: r < rl
      if (rl <= 0) continue;
      const int s0 = slotRow[base];
      const int s1 = (rl > 1) ? (int)slotRow[base + 1] : -1;
      const int s2 = (rl > 2) ? (int)slotRow[base + 2] : -1;
      const int s3 = (rl > 3) ? (int)slotRow[base + 3] : -1;
      const bool m01 = (s1 == s0), m12 = (s2 == s1), m23 = (s3 == s2);
#pragma unroll
      for (int j = 0; j < 8; j++) {
        const int col = wv * 128 + j * 16 + lm;
        float v0 = acc[i][j][0], v1 = acc[i][j][1], v2 = acc[i][j][2], v3 = acc[i][j][3];
        v1 = m01 ? fmaxf(v1, v0) : v1;
        v2 = m12 ? fmaxf(v2, v1) : v2;
        v3 = m23 ? fmaxf(v3, v2) : v3;
        if (!m01)           atomicMax(&maxLds[s0 * MLW + col], encf(v0));
        if (rl > 1 && !m12) atomicMax(&maxLds[s1 * MLW + col], encf(v1));
        if (rl > 2 && !m23) atomicMax(&maxLds[s2 * MLW + col], encf(v2));
        if (rl > 3)         atomicMax(&maxLds[s3 * MLW + col], encf(v3));
      }
    }
  };

  for (int rg = 0; rg < nrg; rg++) {
    const int rbase = rg * 64;
    const int nlive = n - rbase;  // block-uniform -> branch + barriers safe
    if (nlive > 32)      rgBody(rbase, ICst<4>{});
    else if (nlive > 16) rgBody(rbase, ICst<2>{});
    else                 rgBody(rbase, ICst<1>{});
  }
  __syncthreads();  // all segmax atomics complete

  // compress: waves 0,1 own cells [wv*16, +16); single pass over all 512 k-cols.
  if (wv < 2) {
    f32x4 accC[2];
    accC[0] = {0.f, 0.f, 0.f, 0.f};
    accC[1] = {0.f, 0.f, 0.f, 0.f};
#pragma unroll
    for (int ks = 0; ks < 16; ks++) {
      int koff = ks * 32 + lq * 8;
      const unsigned* mp = &maxLds[(wv * 16 + lm) * MLW + koff];
      uint4 m0 = *(const uint4*)mp;
      uint4 m1 = *(const uint4*)(mp + 4);
      unsigned mu[8] = {m0.x, m0.y, m0.z, m0.w, m1.x, m1.y, m1.z, m1.w};
      __hip_bfloat16 af[8];
#pragma unroll
      for (int j = 0; j < 8; j++)
        af[j] = __float2bfloat16(decf(mu[j]) + b4[koff + j]);
      bf16x8 aa = *(const bf16x8*)af;
#pragma unroll
      for (int jn = 0; jn < 2; jn++) {
        bf16x8 b = *(const bf16x8*)(const void*)(WcT + (size_t)(jn * 16 + lm) * 512 + koff);
        accC[jn] = __builtin_amdgcn_mfma_f32_16x16x32_bf16(aa, b, accC[jn], 0, 0, 0);
      }
    }
    // final write: cell = c0 + wv*16 + lq*4 + r, col = jn*16+lm. Empty cells: NaN
    // from decf(0) poisons accC rows -> masked by occ to exact 0.
#pragma unroll
    for (int jn = 0; jn < 2; jn++) {
      float bb = bc[jn * 16 + lm];
#pragma unroll
      for (int r = 0; r < 4; r++) {
        int cell = c0 + wv * 16 + lq * 4 + r;
        int occ = starts[cell + 1] > starts[cell];
        float v = occ ? fmaxf(accC[jn][r] + bb, 0.f) : 0.f;
        comp[((size_t)batch * 65536 + cell) * 32 + jn * 16 + lm] = v;
      }
    }
  }
}

// ---- fused epilogue: blocks [0,2048) = 3x3 maxpool into channels 32..63;
// blocks [2048, 6144) = occupancy transpose (float4) into channels 0..31. ----
__global__ __launch_bounds__(256) void epilogue_write(const float* __restrict__ comp,
                                                      const float* __restrict__ occ,
                                                      float* __restrict__ out) {
  int bid = blockIdx.x;
  if (bid < 2048) {
    __shared__ float tile[32][65];
    int z0 = (bid & 3) * 64, x = (bid >> 2) & 255, b = bid >> 10;
    int f = threadIdx.x & 31, zs = threadIdx.x >> 5;
    for (int zi = 0; zi < 8; zi++) {
      int z = z0 + zi * 8 + zs;
      float m = -3.402823466e38f;
      for (int dx = -1; dx <= 1; dx++) {
        int xx = x + dx;
        if (xx < 0 || xx > 255) continue;
        for (int dz = -1; dz <= 1; dz++) {
          int zz = z + dz;
          if (zz < 0 || zz > 255) continue;
          m = fmaxf(m, comp[(size_t)((b << 16) + (xx << 8) + zz) * 32 + f]);
        }
      }
      tile[f][zi * 8 + zs] = m;
    }
    __syncthreads();
    int f2 = threadIdx.x >> 3, seg = threadIdx.x & 7;
    float* dst = out + ((size_t)(b * 64 + 32 + f2) * 256 + x) * 256 + z0 + seg * 8;
#pragma unroll
    for (int u = 0; u < 8; u++) dst[u] = tile[f2][seg * 8 + u];
  } else {
    int oidx = (bid - 2048) * 256 + threadIdx.x;  // 4096*256 = 1,048,576 threads
    int z4 = oidx & 63, x = (oidx >> 6) & 255, hh = (oidx >> 14) & 31, b = oidx >> 19;
    const float4 v = *(const float4*)(occ + ((((size_t)b * 256 + x) * 32 + hh) * 256 + z4 * 4));
    *(float4*)(out + (((size_t)(b * 64 + hh) * 256 + x) * 256 + z4 * 4)) = v;
  }
}

extern "C" void kernel_launch(void* const* d_in, const int* in_sizes, int n_in,
                              void* d_out, int out_size, void* d_ws, size_t ws_size,
                              hipStream_t stream) {
  const float* pt_fea   = (const float*)d_in[0];
  const int*   grid_ind = (const int*)d_in[1];
  const float* occup    = (const float*)d_in[2];
  const float* W1 = (const float*)d_in[3];  const float* b1 = (const float*)d_in[4];
  const float* W2 = (const float*)d_in[5];  const float* b2 = (const float*)d_in[6];
  const float* W3 = (const float*)d_in[7];  const float* b3 = (const float*)d_in[8];
  const float* W4 = (const float*)d_in[9];  const float* b4 = (const float*)d_in[10];
  const float* g0 = (const float*)d_in[11]; const float* be0 = (const float*)d_in[12];
  const float* g1 = (const float*)d_in[13]; const float* be1 = (const float*)d_in[14];
  const float* g2 = (const float*)d_in[15]; const float* be2 = (const float*)d_in[16];
  const float* g3 = (const float*)d_in[17]; const float* be3 = (const float*)d_in[18];
  const float* Wc = (const float*)d_in[19]; const float* bc = (const float*)d_in[20];
  float* out = (float*)d_out;

  const int nPts = in_sizes[0] / 3;  // 240000
  const int perB = nPts / 2;         // 120000
  const float invN = 1.f / (float)nPts;

  // ---- workspace layout, peak ~215.4 MB ----
  char* ws = (char*)d_ws;
  float* stats = (float*)ws;
  float* scsh  = (float*)(ws + 4096);
  float* sums0 = stats;        float* sums1 = stats + 16;
  float* sums2 = stats + 160;  float* sums3 = stats + 416;
  float* sc0 = scsh;
  float* sc1 = scsh + 16;   float* sh1 = scsh + 80;
  float* sc2 = scsh + 144;  float* sh2 = scsh + 272;
  float* sc3 = scsh + 400;  float* sh3 = scsh + 656;
  __hip_bfloat16* Wt2 = (__hip_bfloat16*)(ws + 8192);     // 16 KB
  __hip_bfloat16* Wt3 = (__hip_bfloat16*)(ws + 24576);    // 64 KB
  __hip_bfloat16* Wt4 = (__hip_bfloat16*)(ws + 90112);    // 256 KB
  __hip_bfloat16* WcT = (__hip_bfloat16*)(ws + 352256);   // 32 KB -> ends 385024
  char* S0 = ws + 385024;
  __hip_bfloat16* Y1 = (__hip_bfloat16*)S0;                    // 30.72 MB
  __hip_bfloat16* Y2 = (__hip_bfloat16*)(S0 + 30720000ll);     // 61.44 MB
  __hip_bfloat16* Y3 = (__hip_bfloat16*)(S0 + 92160000ll);     // 122.88 MB
  // stage-4 aliases over dead Y1 (sort region written only AFTER stage 2 in
  // stream order; comp written only by pool_compress):
  float* comp       = (float*)S0;                              // 16.78 MB
  char* sortBase    = S0 + 17000000ll;                         // inside Y1, after comp
  unsigned* hist    = (unsigned*)sortBase;                     // 2*65536   (512 KB)
  unsigned* cursor  = hist + 2 * 65536;                        // 2*65536   (512 KB)
  unsigned* bSums   = cursor + 2 * 65536;                      // 2*256 (pad 1024)
  unsigned* startsA = bSums + 1024;                            // 2*65537 (pad 131080)
  unsigned* cells   = startsA + 131080;                        // 2*perB    (960 KB)
  unsigned* invPos  = cells + 2 * perB;                        // 2*perB    (960 KB)
  // sort region ends ~S0+20.5 MB < Y1 end (30.72 MB): never touches Y2/Y3.

  hipMemsetAsync(stats, 0, 4096, stream);

  wconv4<<<736, 256, 0, stream>>>(W2, W3, W4, Wc, Wt2, Wt3, Wt4, WcT);

  // stage 0
  stats_feats<<<256, 256, 0, stream>>>(pt_fea, nPts, sums0);
  bn_prep<<<1, 256, 0, stream>>>(sums0, 3, invN, g0, be0, sc0, scsh + 4);

  // stage 1 (fused stats)
  gemm1_stats<<<512, 256, 0, stream>>>(pt_fea, W1, b1, scsh, Y1, nPts, sums1);
  bn_prep<<<1, 256, 0, stream>>>(sums1, 64, invN, g1, be1, sc1, sh1);

  // stage 2 (MFMA, fused stats)
  gemm_mfma<64><<<dim3(nPts / 128, 1), 256, 0, stream>>>(Y1, Wt2, b2, sc1, sh1, Y2, 128, sums2, nPts, nullptr);
  bn_prep<<<1, 256, 0, stream>>>(sums2, 128, invN, g2, be2, sc2, sh2);

  // counting sort BEFORE stage 3 (needs only grid_ind; sort region aliases Y1,
  // which is dead after stage 2 -- memset must come AFTER stage-2 enqueue).
  hipMemsetAsync(hist, 0, 2 * 65536 * 4, stream);
  const int pgrid = (perB + 255) / 256;
  hist_kernel<<<dim3(pgrid, 2), 256, 0, stream>>>(grid_ind, perB, hist);
  scan1<<<dim3(256, 2), 256, 0, stream>>>(hist, cursor, bSums);
  scan2<<<2, 256, 0, stream>>>(bSums);
  mk_starts<<<dim3(256, 2), 256, 0, stream>>>(cursor, bSums, startsA, perB);
  scatter_kernel<<<dim3(pgrid, 2), 256, 0, stream>>>(grid_ind, perB, cursor, bSums, cells, invPos);

  // stage 3 (MFMA, fused stats, PERMUTED write: Y3 lands in sorted order)
  gemm_mfma<128><<<dim3(nPts / 128, 2), 256, 0, stream>>>(Y2, Wt3, b3, sc2, sh2, Y3, 256, sums3, nPts, invPos);
  bn_prep<<<1, 256, 0, stream>>>(sums3, 256, invN, g3, be3, sc3, sh3);

  // fused stage-4: pool + compress, contiguous Y3 reads, run-merged atomics,
  // tail-stripe specialization. 32 cells/block -> (2048, 2).
  pool_compress<<<dim3(2048, 2), 256, 0, stream>>>(
      Y3, Wt4, b4, sc3, sh3, WcT, bc, cells, startsA, comp, perB);

  // fused epilogue: maxpool (2048 blocks) + occupancy transpose (4096 blocks)
  epilogue_write<<<6144, 256, 0, stream>>>(comp, occup, out);
}

// Round 17
// 700.118 us; speedup vs baseline: 1.2860x; 1.2860x over previous
//
#include <hip/hip_runtime.h>
#include <hip/hip_bf16.h>

#define EPSN 1e-5f

typedef __bf16 bf16x8 __attribute__((ext_vector_type(8)));
typedef float f32x4 __attribute__((ext_vector_type(4)));

// ---- order-preserving float<->uint encoding for max pooling ----
// enc sentinel 0u decodes to NaN -> poisons only empty-cell rows, masked at write.
__device__ __forceinline__ unsigned encf(float f) {
  unsigned u = __float_as_uint(f);
  return (u & 0x80000000u) ? ~u : (u | 0x80000000u);
}
__device__ __forceinline__ float decf(unsigned u) {
  return (u & 0x80000000u) ? __uint_as_float(u ^ 0x80000000u) : __uint_as_float(~u);
}

// ---- column stats (sum, sumsq) of the raw 3-feature input ----
__global__ __launch_bounds__(256) void stats_feats(const float* __restrict__ pt, int n,
                                                   float* __restrict__ sums) {
  float a0 = 0, a1 = 0, a2 = 0, q0 = 0, q1 = 0, q2 = 0;
  for (int p = blockIdx.x * 256 + threadIdx.x; p < n; p += gridDim.x * 256) {
    float v0 = pt[3 * p], v1 = pt[3 * p + 1], v2 = pt[3 * p + 2];
    a0 += v0; a1 += v1; a2 += v2;
    q0 += v0 * v0; q1 += v1 * v1; q2 += v2 * v2;
  }
  __shared__ float red[4][6];
  float vals[6] = {a0, a1, a2, q0, q1, q2};
  int lane = threadIdx.x & 63, wv = threadIdx.x >> 6;
#pragma unroll
  for (int k = 0; k < 6; k++) {
    float v = vals[k];
#pragma unroll
    for (int o = 32; o; o >>= 1) v += __shfl_down(v, o, 64);
    if (lane == 0) red[wv][k] = v;
  }
  __syncthreads();
  if (threadIdx.x < 6) {
    float v = red[0][threadIdx.x] + red[1][threadIdx.x] + red[2][threadIdx.x] + red[3][threadIdx.x];
    atomicAdd(&sums[threadIdx.x], v);
  }
}

// ---- fold BN (train-mode batch stats) + affine into per-column scale/shift ----
__global__ void bn_prep(const float* __restrict__ sums, int C, float invN,
                        const float* __restrict__ g, const float* __restrict__ be,
                        float* __restrict__ sc, float* __restrict__ sh) {
  int c = threadIdx.x;
  if (c < C) {
    float m = sums[c] * invN;
    float v = fmaxf(sums[C + c] * invN - m * m, 0.f);
    float s = g[c] * rsqrtf(v + EPSN);
    sc[c] = s;
    sh[c] = be[c] - m * s;
  }
}

// ---- fused weight conversions: fp32 W[K][C] -> bf16 Wt[C][K] for all 4 weights ----
__global__ __launch_bounds__(256) void wconv4(
    const float* __restrict__ W2, const float* __restrict__ W3,
    const float* __restrict__ W4, const float* __restrict__ Wc,
    __hip_bfloat16* __restrict__ Wt2, __hip_bfloat16* __restrict__ Wt3,
    __hip_bfloat16* __restrict__ Wt4, __hip_bfloat16* __restrict__ WcT) {
  int idx = blockIdx.x * 256 + threadIdx.x;
  const float* W; __hip_bfloat16* Wt; int K, C, l;
  if (idx < 8192)        { W = W2; Wt = Wt2; K = 64;  C = 128; l = idx; }
  else if (idx < 40960)  { W = W3; Wt = Wt3; K = 128; C = 256; l = idx - 8192; }
  else if (idx < 172032) { W = W4; Wt = Wt4; K = 256; C = 512; l = idx - 40960; }
  else if (idx < 188416) { W = Wc; Wt = WcT; K = 512; C = 32;  l = idx - 172032; }
  else return;
  int k = l / C, c = l - k * C;
  Wt[(size_t)c * K + k] = __float2bfloat16(W[l]);
}

// ---- stage 1 fused: Y1 = BN(feats)@W1 + b1, column stats inline ----
__global__ __launch_bounds__(256) void gemm1_stats(const float* __restrict__ pt,
                                                   const float* __restrict__ W,
                                                   const float* __restrict__ bias,
                                                   const float* __restrict__ scsh,
                                                   __hip_bfloat16* __restrict__ Y,
                                                   int n, float* __restrict__ sums) {
  const int c = threadIdx.x & 63;
  const float w0 = W[c], w1 = W[64 + c], w2 = W[128 + c], bb = bias[c];
  const float s0 = scsh[0], s1 = scsh[1], s2 = scsh[2];
  const float h0 = scsh[4], h1 = scsh[5], h2 = scsh[6];
  float s = 0.f, q = 0.f;
  const int total = n * 64;
  for (int idx = blockIdx.x * 256 + threadIdx.x; idx < total; idx += gridDim.x * 256) {
    int p = idx >> 6;
    float x0 = s0 * pt[3 * p]     + h0;
    float x1 = s1 * pt[3 * p + 1] + h1;
    float x2 = s2 * pt[3 * p + 2] + h2;
    float y = bb + x0 * w0 + x1 * w1 + x2 * w2;
    Y[idx] = __float2bfloat16(y);
    s += y; q += y * y;
  }
  __shared__ float sred[4][64], qred[4][64];
  int wv = threadIdx.x >> 6;
  sred[wv][c] = s; qred[wv][c] = q;
  __syncthreads();
  if (threadIdx.x < 64) {
    float S = sred[0][c] + sred[1][c] + sred[2][c] + sred[3][c];
    float Q = qred[0][c] + qred[1][c] + qred[2][c] + qred[3][c];
    atomicAdd(&sums[c], S);
    atomicAdd(&sums[64 + c], Q);
  }
}

// ---- MFMA GEMM (stages 2/3): Yout = relu(sc*Yin+sh)@W + bias, fused column stats.
// Output staged through LDS, contiguous 64B/lane stores. Optional perm: output
// row i lands at row perm[i] (stage 3 writes Y3 in SORTED order so stage 4 reads
// are contiguous -- write-side scatter is fire-and-forget). ----
template <int K>
__global__ __launch_bounds__(256) void gemm_mfma(
    const __hip_bfloat16* __restrict__ Yin, const __hip_bfloat16* __restrict__ Wt,
    const float* __restrict__ bias, const float* __restrict__ sc, const float* __restrict__ sh,
    __hip_bfloat16* __restrict__ Yout, int C, float* __restrict__ sums, int nrows,
    const unsigned* __restrict__ perm) {
  constexpr int KS = 64, LDA = 72, LDO = 80;
  __shared__ __align__(16) __hip_bfloat16 hA[128 * LDO];
  __shared__ float sredArr[128], qredArr[128];
  const int t = threadIdx.x;
  const int lane = t & 63, wv = t >> 6;
  const int mh = (wv >> 1) * 64, nh = (wv & 1) * 64;
  const int lm = lane & 15, lq = lane >> 4;
  const int p0 = blockIdx.x * 128;
  const int cb0 = blockIdx.y * 128;

  f32x4 acc[4][4];
#pragma unroll
  for (int i = 0; i < 4; i++)
#pragma unroll
    for (int j = 0; j < 4; j++) acc[i][j] = {0.f, 0.f, 0.f, 0.f};

  for (int k0 = 0; k0 < K; k0 += KS) {
    __syncthreads();
#pragma unroll
    for (int it = 0; it < 4; it++) {
      int idx = it * 256 + t;
      int row = idx >> 3;
      int c8 = (idx & 7) * 8;
      int gp = p0 + row;
      __hip_bfloat16 h8[8];
      if (gp < nrows) {
        uint4 raw = *(const uint4*)(Yin + (size_t)gp * K + k0 + c8);
        const __hip_bfloat16* pr = (const __hip_bfloat16*)&raw;
#pragma unroll
        for (int j = 0; j < 8; j++) {
          float v = sc[k0 + c8 + j] * __bfloat162float(pr[j]) + sh[k0 + c8 + j];
          h8[j] = __float2bfloat16(fmaxf(v, 0.f));
        }
      } else {
#pragma unroll
        for (int j = 0; j < 8; j++) h8[j] = __float2bfloat16(0.f);
      }
      *(uint4*)&hA[row * LDA + c8] = *(const uint4*)h8;
    }
    __syncthreads();
#pragma unroll
    for (int kk = 0; kk < KS; kk += 32) {
      bf16x8 a[4], b[4];
#pragma unroll
      for (int i = 0; i < 4; i++)
        a[i] = *(const bf16x8*)&hA[(mh + i * 16 + lm) * LDA + kk + lq * 8];
#pragma unroll
      for (int j = 0; j < 4; j++)
        b[j] = *(const bf16x8*)(const void*)(Wt + (size_t)(cb0 + nh + j * 16 + lm) * K + k0 + kk + lq * 8);
#pragma unroll
      for (int i = 0; i < 4; i++)
#pragma unroll
        for (int j = 0; j < 4; j++)
          acc[i][j] = __builtin_amdgcn_mfma_f32_16x16x32_bf16(a[i], b[j], acc[i][j], 0, 0, 0);
    }
  }

#pragma unroll
  for (int j = 0; j < 4; j++) {
    float bb = bias[cb0 + nh + j * 16 + lm];
#pragma unroll
    for (int i = 0; i < 4; i++)
#pragma unroll
      for (int r = 0; r < 4; r++) acc[i][j][r] += bb;
  }

  __syncthreads();
  if (t < 128) { sredArr[t] = 0.f; qredArr[t] = 0.f; }
  __syncthreads();

#pragma unroll
  for (int j = 0; j < 4; j++) {
    float s = 0.f, q = 0.f;
#pragma unroll
    for (int i = 0; i < 4; i++)
#pragma unroll
      for (int r = 0; r < 4; r++) {
        int grow = p0 + mh + i * 16 + lq * 4 + r;
        if (grow < nrows) { float v = acc[i][j][r]; s += v; q += v * v; }
      }
    s += __shfl_xor(s, 16); s += __shfl_xor(s, 32);
    q += __shfl_xor(q, 16); q += __shfl_xor(q, 32);
    if (lq == 0) {
      atomicAdd(&sredArr[nh + j * 16 + lm], s);
      atomicAdd(&qredArr[nh + j * 16 + lm], q);
    }
  }

  for (int half = 0; half < 2; half++) {
    __syncthreads();
    if ((wv & 1) == half) {
#pragma unroll
      for (int j = 0; j < 4; j++)
#pragma unroll
        for (int i = 0; i < 4; i++)
#pragma unroll
          for (int r = 0; r < 4; r++)
            hA[(mh + i * 16 + lq * 4 + r) * LDO + j * 16 + lm] = __float2bfloat16(acc[i][j][r]);
    }
    __syncthreads();
    int row = t >> 1, seg = t & 1;
    int gp = p0 + row;
    if (gp < nrows) {
      size_t drow = perm ? (size_t)perm[gp] : (size_t)gp;
      const uint4* src = (const uint4*)&hA[row * LDO + seg * 32];
      uint4* dst = (uint4*)(Yout + drow * C + cb0 + half * 64 + seg * 32);
      dst[0] = src[0]; dst[1] = src[1]; dst[2] = src[2]; dst[3] = src[3];
    }
  }

  if (t < 128) {
    atomicAdd(&sums[cb0 + t], sredArr[t]);
    atomicAdd(&sums[C + cb0 + t], qredArr[t]);
  }
}

// ---- counting sort (batched over blockIdx.y) ----
__global__ __launch_bounds__(256) void hist_kernel(const int* __restrict__ gi, int perB,
                                                   unsigned* __restrict__ hist) {
  int b = blockIdx.y;
  int p = blockIdx.x * 256 + threadIdx.x;
  if (p < perB) {
    int gp = b * perB + p;
    int c = (gi[2 * gp] & 255) * 256 + (gi[2 * gp + 1] & 255);
    atomicAdd(&hist[b * 65536 + c], 1u);
  }
}
__global__ __launch_bounds__(256) void scan1(const unsigned* __restrict__ hist,
                                             unsigned* __restrict__ cursor,
                                             unsigned* __restrict__ bSums) {
  __shared__ unsigned s[256];
  int b = blockIdx.y;
  int t = threadIdx.x, i = b * 65536 + blockIdx.x * 256 + t;
  unsigned v = hist[i]; s[t] = v; __syncthreads();
  for (int off = 1; off < 256; off <<= 1) {
    unsigned x = (t >= off) ? s[t - off] : 0u; __syncthreads();
    s[t] += x; __syncthreads();
  }
  cursor[i] = s[t] - v;
  if (t == 255) bSums[b * 256 + blockIdx.x] = s[255];
}
__global__ void scan2(unsigned* __restrict__ bSums) {  // grid = 2 blocks (one per batch)
  __shared__ unsigned s[256];
  int t = threadIdx.x, i = blockIdx.x * 256 + t;
  unsigned v = bSums[i]; s[t] = v; __syncthreads();
  for (int off = 1; off < 256; off <<= 1) {
    unsigned x = (t >= off) ? s[t - off] : 0u; __syncthreads();
    s[t] += x; __syncthreads();
  }
  bSums[i] = s[t] - v;
}
// starts[b][c] = global exclusive prefix; starts[b][65536] = perB  (runs BEFORE scatter)
__global__ __launch_bounds__(256) void mk_starts(const unsigned* __restrict__ cursor,
                                                 const unsigned* __restrict__ bSums,
                                                 unsigned* __restrict__ starts, int perB) {
  int b = blockIdx.y;
  int i = blockIdx.x * 256 + threadIdx.x;
  starts[b * 65537 + i] = cursor[b * 65536 + i] + bSums[b * 256 + (i >> 8)];
  if (i == 0) starts[b * 65537 + 65536] = (unsigned)perB;
}
// scatter: cells[sorted position] = cell id; invPos[point] = global sorted row.
__global__ __launch_bounds__(256) void scatter_kernel(const int* __restrict__ gi, int perB,
                                                      unsigned* __restrict__ cursor,
                                                      const unsigned* __restrict__ bSums,
                                                      unsigned* __restrict__ cells,
                                                      unsigned* __restrict__ invPos) {
  int b = blockIdx.y;
  int p = blockIdx.x * 256 + threadIdx.x;
  if (p < perB) {
    int gp = b * perB + p;
    int c = (gi[2 * gp] & 255) * 256 + (gi[2 * gp + 1] & 255);
    unsigned pos = atomicAdd(&cursor[b * 65536 + c], 1u) + bSums[b * 256 + (c >> 8)];
    if (pos >= (unsigned)perB) pos = (unsigned)perB - 1u;  // fault insurance: never triggers
    cells[b * perB + pos] = (unsigned)c;
    invPos[gp] = (unsigned)(b * perB) + pos;
  }
}

// ---- fused stage-4 (EXACT r15 body -- proven 290us, 116 VGPR, zero spill):
// 32 exclusive cells, M=64, 256 thr, LDS 76.8 KB, (256,2). Y3 sorted ->
// contiguous staging; run-merged atomics (consecutive sorted rows share a cell,
// avg run 1.83: fold same-cell neighbors in-register, one atomic per run ->
// 128 -> ~86 atomic insts/wave/rg). r16 lesson: ANY structural reshaping of
// this body (templated stripe counts) re-perturbs the allocator past the
// (256,2) wall -> spill; the loop shape itself is part of the proven config. ----
__global__ __launch_bounds__(256, 2) void pool_compress(
    const __hip_bfloat16* __restrict__ Y3, const __hip_bfloat16* __restrict__ Wt4,
    const float* __restrict__ b4, const float* __restrict__ sc, const float* __restrict__ sh,
    const __hip_bfloat16* __restrict__ WcT, const float* __restrict__ bc,
    const unsigned* __restrict__ sortedCell, const unsigned* __restrict__ startsAll,
    float* __restrict__ comp, int perB) {
  constexpr int K = 256, KS = 64, LDA = 72, MLW = 516;
  __shared__ __align__(16) __hip_bfloat16 hA[64 * LDA];   // 9.2 KB
  __shared__ __align__(16) unsigned maxLds[32 * MLW];     // 66.0 KB
  __shared__ unsigned char slotRow[256];
  const int t = threadIdx.x;
  const int lane = t & 63, wv = t >> 6;  // wave grid 1M x 4N: wave wv owns cols [wv*128, +128)
  const int lm = lane & 15, lq = lane >> 4;
  const int batch = blockIdx.y;
  const unsigned* starts = startsAll + batch * 65537;
  const int c0 = blockIdx.x * 32;
  const int r0 = (int)starts[c0];
  int n = (int)starts[c0 + 32] - r0;
  if (n > 256) n = 256;  // safety clamp (32 cells, ~59 pts avg: never hit)
  if (n < 0) n = 0;
  const int nrg = (n + 63) >> 6;
  const size_t rowBase = (size_t)batch * perB + r0;

  for (int i = t; i < n; i += 256)
    slotRow[i] = (unsigned char)((sortedCell[batch * perB + r0 + i] - c0) & 31);
  {
    const uint4 z4 = {0u, 0u, 0u, 0u};
    for (int i = t * 4; i < 32 * MLW; i += 1024) *(uint4*)&maxLds[i] = z4;
  }

  for (int rg = 0; rg < nrg; rg++) {
    const int rbase = rg * 64;
    f32x4 acc[4][8];
#pragma unroll
    for (int i = 0; i < 4; i++)
#pragma unroll
      for (int j = 0; j < 8; j++) acc[i][j] = {0.f, 0.f, 0.f, 0.f};
    for (int k0 = 0; k0 < K; k0 += KS) {
      __syncthreads();  // hA free (covers init/zeroing on first pass, prior reads after)
#pragma unroll
      for (int it = 0; it < 2; it++) {
        int idx = it * 256 + t;
        int row = idx >> 3;
        int c8 = (idx & 7) * 8;
        int gr = rbase + row;
        __hip_bfloat16 h8[8];
        if (gr < n) {
          uint4 raw = *(const uint4*)(Y3 + (rowBase + gr) * K + k0 + c8);
          const __hip_bfloat16* pr = (const __hip_bfloat16*)&raw;
#pragma unroll
          for (int j = 0; j < 8; j++) {
            float v = sc[k0 + c8 + j] * __bfloat162float(pr[j]) + sh[k0 + c8 + j];
            h8[j] = __float2bfloat16(fmaxf(v, 0.f));
          }
        } else {
#pragma unroll
          for (int j = 0; j < 8; j++) h8[j] = __float2bfloat16(0.f);
        }
        *(uint4*)&hA[row * LDA + c8] = *(const uint4*)h8;
      }
      __syncthreads();
#pragma unroll
      for (int kk = 0; kk < KS; kk += 32) {
        bf16x8 a[4];
#pragma unroll
        for (int i = 0; i < 4; i++)
          a[i] = *(const bf16x8*)&hA[(i * 16 + lm) * LDA + kk + lq * 8];
#pragma unroll
        for (int j = 0; j < 8; j++) {
          bf16x8 b = *(const bf16x8*)(const void*)(Wt4 + (size_t)(wv * 128 + j * 16 + lm) * K + k0 + kk + lq * 8);
#pragma unroll
          for (int i = 0; i < 4; i++)
            acc[i][j] = __builtin_amdgcn_mfma_f32_16x16x32_bf16(a[i], b, acc[i][j], 0, 0, 0);
        }
      }
    }
    // segmented max with run-merging (raw h4; bias folded at compress).
    // Rows of one f32x4 are consecutive -> fold same-cell neighbors in-register,
    // emit one atomic per run. Conditions uniform across j (hoisted).
#pragma unroll
    for (int i = 0; i < 4; i++) {
      const int base = rbase + i * 16 + lq * 4;
      const int rl = n - base;  // rows valid: r < rl
      if (rl <= 0) continue;
      const int s0 = slotRow[base];
      const int s1 = (rl > 1) ? (int)slotRow[base + 1] : -1;
      const int s2 = (rl > 2) ? (int)slotRow[base + 2] : -1;
      const int s3 = (rl > 3) ? (int)slotRow[base + 3] : -1;
      const bool m01 = (s1 == s0), m12 = (s2 == s1), m23 = (s3 == s2);
#pragma unroll
      for (int j = 0; j < 8; j++) {
        const int col = wv * 128 + j * 16 + lm;
        float v0 = acc[i][j][0], v1 = acc[i][j][1], v2 = acc[i][j][2], v3 = acc[i][j][3];
        v1 = m01 ? fmaxf(v1, v0) : v1;
        v2 = m12 ? fmaxf(v2, v1) : v2;
        v3 = m23 ? fmaxf(v3, v2) : v3;
        if (!m01)           atomicMax(&maxLds[s0 * MLW + col], encf(v0));
        if (rl > 1 && !m12) atomicMax(&maxLds[s1 * MLW + col], encf(v1));
        if (rl > 2 && !m23) atomicMax(&maxLds[s2 * MLW + col], encf(v2));
        if (rl > 3)         atomicMax(&maxLds[s3 * MLW + col], encf(v3));
      }
    }
  }
  __syncthreads();  // all segmax atomics complete

  // compress: waves 0,1 own cells [wv*16, +16); single pass over all 512 k-cols.
  if (wv < 2) {
    f32x4 accC[2];
    accC[0] = {0.f, 0.f, 0.f, 0.f};
    accC[1] = {0.f, 0.f, 0.f, 0.f};
#pragma unroll
    for (int ks = 0; ks < 16; ks++) {
      int koff = ks * 32 + lq * 8;
      const unsigned* mp = &maxLds[(wv * 16 + lm) * MLW + koff];
      uint4 m0 = *(const uint4*)mp;
      uint4 m1 = *(const uint4*)(mp + 4);
      unsigned mu[8] = {m0.x, m0.y, m0.z, m0.w, m1.x, m1.y, m1.z, m1.w};
      __hip_bfloat16 af[8];
#pragma unroll
      for (int j = 0; j < 8; j++)
        af[j] = __float2bfloat16(decf(mu[j]) + b4[koff + j]);
      bf16x8 aa = *(const bf16x8*)af;
#pragma unroll
      for (int jn = 0; jn < 2; jn++) {
        bf16x8 b = *(const bf16x8*)(const void*)(WcT + (size_t)(jn * 16 + lm) * 512 + koff);
        accC[jn] = __builtin_amdgcn_mfma_f32_16x16x32_bf16(aa, b, accC[jn], 0, 0, 0);
      }
    }
    // final write: cell = c0 + wv*16 + lq*4 + r, col = jn*16+lm. Empty cells: NaN
    // from decf(0) poisons accC rows -> masked by occ to exact 0.
#pragma unroll
    for (int jn = 0; jn < 2; jn++) {
      float bb = bc[jn * 16 + lm];
#pragma unroll
      for (int r = 0; r < 4; r++) {
        int cell = c0 + wv * 16 + lq * 4 + r;
        int occ = starts[cell + 1] > starts[cell];
        float v = occ ? fmaxf(accC[jn][r] + bb, 0.f) : 0.f;
        comp[((size_t)batch * 65536 + cell) * 32 + jn * 16 + lm] = v;
      }
    }
  }
}

// ---- fused epilogue: blocks [0,2048) = 3x3 maxpool into channels 32..63;
// blocks [2048, 6144) = occupancy transpose (float4) into channels 0..31. ----
__global__ __launch_bounds__(256) void epilogue_write(const float* __restrict__ comp,
                                                      const float* __restrict__ occ,
                                                      float* __restrict__ out) {
  int bid = blockIdx.x;
  if (bid < 2048) {
    __shared__ float tile[32][65];
    int z0 = (bid & 3) * 64, x = (bid >> 2) & 255, b = bid >> 10;
    int f = threadIdx.x & 31, zs = threadIdx.x >> 5;
    for (int zi = 0; zi < 8; zi++) {
      int z = z0 + zi * 8 + zs;
      float m = -3.402823466e38f;
      for (int dx = -1; dx <= 1; dx++) {
        int xx = x + dx;
        if (xx < 0 || xx > 255) continue;
        for (int dz = -1; dz <= 1; dz++) {
          int zz = z + dz;
          if (zz < 0 || zz > 255) continue;
          m = fmaxf(m, comp[(size_t)((b << 16) + (xx << 8) + zz) * 32 + f]);
        }
      }
      tile[f][zi * 8 + zs] = m;
    }
    __syncthreads();
    int f2 = threadIdx.x >> 3, seg = threadIdx.x & 7;
    float* dst = out + ((size_t)(b * 64 + 32 + f2) * 256 + x) * 256 + z0 + seg * 8;
#pragma unroll
    for (int u = 0; u < 8; u++) dst[u] = tile[f2][seg * 8 + u];
  } else {
    int oidx = (bid - 2048) * 256 + threadIdx.x;  // 4096*256 = 1,048,576 threads
    int z4 = oidx & 63, x = (oidx >> 6) & 255, hh = (oidx >> 14) & 31, b = oidx >> 19;
    const float4 v = *(const float4*)(occ + ((((size_t)b * 256 + x) * 32 + hh) * 256 + z4 * 4));
    *(float4*)(out + (((size_t)(b * 64 + hh) * 256 + x) * 256 + z4 * 4)) = v;
  }
}

extern "C" void kernel_launch(void* const* d_in, const int* in_sizes, int n_in,
                              void* d_out, int out_size, void* d_ws, size_t ws_size,
                              hipStream_t stream) {
  const float* pt_fea   = (const float*)d_in[0];
  const int*   grid_ind = (const int*)d_in[1];
  const float* occup    = (const float*)d_in[2];
  const float* W1 = (const float*)d_in[3];  const float* b1 = (const float*)d_in[4];
  const float* W2 = (const float*)d_in[5];  const float* b2 = (const float*)d_in[6];
  const float* W3 = (const float*)d_in[7];  const float* b3 = (const float*)d_in[8];
  const float* W4 = (const float*)d_in[9];  const float* b4 = (const float*)d_in[10];
  const float* g0 = (const float*)d_in[11]; const float* be0 = (const float*)d_in[12];
  const float* g1 = (const float*)d_in[13]; const float* be1 = (const float*)d_in[14];
  const float* g2 = (const float*)d_in[15]; const float* be2 = (const float*)d_in[16];
  const float* g3 = (const float*)d_in[17]; const float* be3 = (const float*)d_in[18];
  const float* Wc = (const float*)d_in[19]; const float* bc = (const float*)d_in[20];
  float* out = (float*)d_out;

  const int nPts = in_sizes[0] / 3;  // 240000
  const int perB = nPts / 2;         // 120000
  const float invN = 1.f / (float)nPts;

  // ---- workspace layout, peak ~215.4 MB ----
  char* ws = (char*)d_ws;
  float* stats = (float*)ws;
  float* scsh  = (float*)(ws + 4096);
  float* sums0 = stats;        float* sums1 = stats + 16;
  float* sums2 = stats + 160;  float* sums3 = stats + 416;
  float* sc0 = scsh;
  float* sc1 = scsh + 16;   float* sh1 = scsh + 80;
  float* sc2 = scsh + 144;  float* sh2 = scsh + 272;
  float* sc3 = scsh + 400;  float* sh3 = scsh + 656;
  __hip_bfloat16* Wt2 = (__hip_bfloat16*)(ws + 8192);     // 16 KB
  __hip_bfloat16* Wt3 = (__hip_bfloat16*)(ws + 24576);    // 64 KB
  __hip_bfloat16* Wt4 = (__hip_bfloat16*)(ws + 90112);    // 256 KB
  __hip_bfloat16* WcT = (__hip_bfloat16*)(ws + 352256);   // 32 KB -> ends 385024
  char* S0 = ws + 385024;
  __hip_bfloat16* Y1 = (__hip_bfloat16*)S0;                    // 30.72 MB
  __hip_bfloat16* Y2 = (__hip_bfloat16*)(S0 + 30720000ll);     // 61.44 MB
  __hip_bfloat16* Y3 = (__hip_bfloat16*)(S0 + 92160000ll);     // 122.88 MB
  // stage-4 aliases over dead Y1 (sort region written only AFTER stage 2 in
  // stream order; comp written only by pool_compress):
  float* comp       = (float*)S0;                              // 16.78 MB
  char* sortBase    = S0 + 17000000ll;                         // inside Y1, after comp
  unsigned* hist    = (unsigned*)sortBase;                     // 2*65536   (512 KB)
  unsigned* cursor  = hist + 2 * 65536;                        // 2*65536   (512 KB)
  unsigned* bSums   = cursor + 2 * 65536;                      // 2*256 (pad 1024)
  unsigned* startsA = bSums + 1024;                            // 2*65537 (pad 131080)
  unsigned* cells   = startsA + 131080;                        // 2*perB    (960 KB)
  unsigned* invPos  = cells + 2 * perB;                        // 2*perB    (960 KB)
  // sort region ends ~S0+20.5 MB < Y1 end (30.72 MB): never touches Y2/Y3.

  hipMemsetAsync(stats, 0, 4096, stream);

  wconv4<<<736, 256, 0, stream>>>(W2, W3, W4, Wc, Wt2, Wt3, Wt4, WcT);

  // stage 0
  stats_feats<<<256, 256, 0, stream>>>(pt_fea, nPts, sums0);
  bn_prep<<<1, 256, 0, stream>>>(sums0, 3, invN, g0, be0, sc0, scsh + 4);

  // stage 1 (fused stats)
  gemm1_stats<<<512, 256, 0, stream>>>(pt_fea, W1, b1, scsh, Y1, nPts, sums1);
  bn_prep<<<1, 256, 0, stream>>>(sums1, 64, invN, g1, be1, sc1, sh1);

  // stage 2 (MFMA, fused stats)
  gemm_mfma<64><<<dim3(nPts / 128, 1), 256, 0, stream>>>(Y1, Wt2, b2, sc1, sh1, Y2, 128, sums2, nPts, nullptr);
  bn_prep<<<1, 256, 0, stream>>>(sums2, 128, invN, g2, be2, sc2, sh2);

  // counting sort BEFORE stage 3 (needs only grid_ind; sort region aliases Y1,
  // which is dead after stage 2 -- memset must come AFTER stage-2 enqueue).
  hipMemsetAsync(hist, 0, 2 * 65536 * 4, stream);
  const int pgrid = (perB + 255) / 256;
  hist_kernel<<<dim3(pgrid, 2), 256, 0, stream>>>(grid_ind, perB, hist);
  scan1<<<dim3(256, 2), 256, 0, stream>>>(hist, cursor, bSums);
  scan2<<<2, 256, 0, stream>>>(bSums);
  mk_starts<<<dim3(256, 2), 256, 0, stream>>>(cursor, bSums, startsA, perB);
  scatter_kernel<<<dim3(pgrid, 2), 256, 0, stream>>>(grid_ind, perB, cursor, bSums, cells, invPos);

  // stage 3 (MFMA, fused stats, PERMUTED write: Y3 lands in sorted order)
  gemm_mfma<128><<<dim3(nPts / 128, 2), 256, 0, stream>>>(Y2, Wt3, b3, sc2, sh2, Y3, 256, sums3, nPts, invPos);
  bn_prep<<<1, 256, 0, stream>>>(sums3, 256, invN, g3, be3, sc3, sh3);

  // fused stage-4: pool + compress, contiguous Y3 reads, run-merged atomics.
  // 32 cells/block -> (2048, 2).
  pool_compress<<<dim3(2048, 2), 256, 0, stream>>>(
      Y3, Wt4, b4, sc3, sh3, WcT, bc, cells, startsA, comp, perB);

  // fused epilogue: maxpool (2048 blocks) + occupancy transpose (4096 blocks)
  epilogue_write<<<6144, 256, 0, stream>>>(comp, occup, out);
}

// Round 18
// 698.460 us; speedup vs baseline: 1.2891x; 1.0024x over previous
//
#include <hip/hip_runtime.h>
#include <hip/hip_bf16.h>

#define EPSN 1e-5f

typedef __bf16 bf16x8 __attribute__((ext_vector_type(8)));
typedef float f32x4 __attribute__((ext_vector_type(4)));

// ---- order-preserving float<->uint encoding for max pooling ----
// enc sentinel 0u decodes to NaN -> poisons only empty-cell rows, masked at write.
__device__ __forceinline__ unsigned encf(float f) {
  unsigned u = __float_as_uint(f);
  return (u & 0x80000000u) ? ~u : (u | 0x80000000u);
}
__device__ __forceinline__ float decf(unsigned u) {
  return (u & 0x80000000u) ? __uint_as_float(u ^ 0x80000000u) : __uint_as_float(~u);
}

// ---- column stats (sum, sumsq) of the raw 3-feature input ----
__global__ __launch_bounds__(256) void stats_feats(const float* __restrict__ pt, int n,
                                                   float* __restrict__ sums) {
  float a0 = 0, a1 = 0, a2 = 0, q0 = 0, q1 = 0, q2 = 0;
  for (int p = blockIdx.x * 256 + threadIdx.x; p < n; p += gridDim.x * 256) {
    float v0 = pt[3 * p], v1 = pt[3 * p + 1], v2 = pt[3 * p + 2];
    a0 += v0; a1 += v1; a2 += v2;
    q0 += v0 * v0; q1 += v1 * v1; q2 += v2 * v2;
  }
  __shared__ float red[4][6];
  float vals[6] = {a0, a1, a2, q0, q1, q2};
  int lane = threadIdx.x & 63, wv = threadIdx.x >> 6;
#pragma unroll
  for (int k = 0; k < 6; k++) {
    float v = vals[k];
#pragma unroll
    for (int o = 32; o; o >>= 1) v += __shfl_down(v, o, 64);
    if (lane == 0) red[wv][k] = v;
  }
  __syncthreads();
  if (threadIdx.x < 6) {
    float v = red[0][threadIdx.x] + red[1][threadIdx.x] + red[2][threadIdx.x] + red[3][threadIdx.x];
    atomicAdd(&sums[threadIdx.x], v);
  }
}

// ---- fold BN (train-mode batch stats) + affine into per-column scale/shift ----
__global__ void bn_prep(const float* __restrict__ sums, int C, float invN,
                        const float* __restrict__ g, const float* __restrict__ be,
                        float* __restrict__ sc, float* __restrict__ sh) {
  int c = threadIdx.x;
  if (c < C) {
    float m = sums[c] * invN;
    float v = fmaxf(sums[C + c] * invN - m * m, 0.f);
    float s = g[c] * rsqrtf(v + EPSN);
    sc[c] = s;
    sh[c] = be[c] - m * s;
  }
}

// ---- fused weight conversions: fp32 W[K][C] -> bf16 Wt[C][K] for all 4 weights ----
__global__ __launch_bounds__(256) void wconv4(
    const float* __restrict__ W2, const float* __restrict__ W3,
    const float* __restrict__ W4, const float* __restrict__ Wc,
    __hip_bfloat16* __restrict__ Wt2, __hip_bfloat16* __restrict__ Wt3,
    __hip_bfloat16* __restrict__ Wt4, __hip_bfloat16* __restrict__ WcT) {
  int idx = blockIdx.x * 256 + threadIdx.x;
  const float* W; __hip_bfloat16* Wt; int K, C, l;
  if (idx < 8192)        { W = W2; Wt = Wt2; K = 64;  C = 128; l = idx; }
  else if (idx < 40960)  { W = W3; Wt = Wt3; K = 128; C = 256; l = idx - 8192; }
  else if (idx < 172032) { W = W4; Wt = Wt4; K = 256; C = 512; l = idx - 40960; }
  else if (idx < 188416) { W = Wc; Wt = WcT; K = 512; C = 32;  l = idx - 172032; }
  else return;
  int k = l / C, c = l - k * C;
  Wt[(size_t)c * K + k] = __float2bfloat16(W[l]);
}

// ---- stage 1 fused: Y1 = BN(feats)@W1 + b1, column stats inline ----
__global__ __launch_bounds__(256) void gemm1_stats(const float* __restrict__ pt,
                                                   const float* __restrict__ W,
                                                   const float* __restrict__ bias,
                                                   const float* __restrict__ scsh,
                                                   __hip_bfloat16* __restrict__ Y,
                                                   int n, float* __restrict__ sums) {
  const int c = threadIdx.x & 63;
  const float w0 = W[c], w1 = W[64 + c], w2 = W[128 + c], bb = bias[c];
  const float s0 = scsh[0], s1 = scsh[1], s2 = scsh[2];
  const float h0 = scsh[4], h1 = scsh[5], h2 = scsh[6];
  float s = 0.f, q = 0.f;
  const int total = n * 64;
  for (int idx = blockIdx.x * 256 + threadIdx.x; idx < total; idx += gridDim.x * 256) {
    int p = idx >> 6;
    float x0 = s0 * pt[3 * p]     + h0;
    float x1 = s1 * pt[3 * p + 1] + h1;
    float x2 = s2 * pt[3 * p + 2] + h2;
    float y = bb + x0 * w0 + x1 * w1 + x2 * w2;
    Y[idx] = __float2bfloat16(y);
    s += y; q += y * y;
  }
  __shared__ float sred[4][64], qred[4][64];
  int wv = threadIdx.x >> 6;
  sred[wv][c] = s; qred[wv][c] = q;
  __syncthreads();
  if (threadIdx.x < 64) {
    float S = sred[0][c] + sred[1][c] + sred[2][c] + sred[3][c];
    float Q = qred[0][c] + qred[1][c] + qred[2][c] + qred[3][c];
    atomicAdd(&sums[c], S);
    atomicAdd(&sums[64 + c], Q);
  }
}

// ---- MFMA GEMM (stages 2/3): Yout = relu(sc*Yin+sh)@W + bias, fused column stats.
// Output staged through LDS, contiguous 64B/lane stores. Optional perm: output
// row i lands at row perm[i] (stage 3 writes Y3 in SORTED order so stage 4 reads
// are contiguous -- write-side scatter is fire-and-forget). ----
template <int K>
__global__ __launch_bounds__(256) void gemm_mfma(
    const __hip_bfloat16* __restrict__ Yin, const __hip_bfloat16* __restrict__ Wt,
    const float* __restrict__ bias, const float* __restrict__ sc, const float* __restrict__ sh,
    __hip_bfloat16* __restrict__ Yout, int C, float* __restrict__ sums, int nrows,
    const unsigned* __restrict__ perm) {
  constexpr int KS = 64, LDA = 72, LDO = 80;
  __shared__ __align__(16) __hip_bfloat16 hA[128 * LDO];
  __shared__ float sredArr[128], qredArr[128];
  const int t = threadIdx.x;
  const int lane = t & 63, wv = t >> 6;
  const int mh = (wv >> 1) * 64, nh = (wv & 1) * 64;
  const int lm = lane & 15, lq = lane >> 4;
  const int p0 = blockIdx.x * 128;
  const int cb0 = blockIdx.y * 128;

  f32x4 acc[4][4];
#pragma unroll
  for (int i = 0; i < 4; i++)
#pragma unroll
    for (int j = 0; j < 4; j++) acc[i][j] = {0.f, 0.f, 0.f, 0.f};

  for (int k0 = 0; k0 < K; k0 += KS) {
    __syncthreads();
#pragma unroll
    for (int it = 0; it < 4; it++) {
      int idx = it * 256 + t;
      int row = idx >> 3;
      int c8 = (idx & 7) * 8;
      int gp = p0 + row;
      __hip_bfloat16 h8[8];
      if (gp < nrows) {
        uint4 raw = *(const uint4*)(Yin + (size_t)gp * K + k0 + c8);
        const __hip_bfloat16* pr = (const __hip_bfloat16*)&raw;
#pragma unroll
        for (int j = 0; j < 8; j++) {
          float v = sc[k0 + c8 + j] * __bfloat162float(pr[j]) + sh[k0 + c8 + j];
          h8[j] = __float2bfloat16(fmaxf(v, 0.f));
        }
      } else {
#pragma unroll
        for (int j = 0; j < 8; j++) h8[j] = __float2bfloat16(0.f);
      }
      *(uint4*)&hA[row * LDA + c8] = *(const uint4*)h8;
    }
    __syncthreads();
#pragma unroll
    for (int kk = 0; kk < KS; kk += 32) {
      bf16x8 a[4], b[4];
#pragma unroll
      for (int i = 0; i < 4; i++)
        a[i] = *(const bf16x8*)&hA[(mh + i * 16 + lm) * LDA + kk + lq * 8];
#pragma unroll
      for (int j = 0; j < 4; j++)
        b[j] = *(const bf16x8*)(const void*)(Wt + (size_t)(cb0 + nh + j * 16 + lm) * K + k0 + kk + lq * 8);
#pragma unroll
      for (int i = 0; i < 4; i++)
#pragma unroll
        for (int j = 0; j < 4; j++)
          acc[i][j] = __builtin_amdgcn_mfma_f32_16x16x32_bf16(a[i], b[j], acc[i][j], 0, 0, 0);
    }
  }

#pragma unroll
  for (int j = 0; j < 4; j++) {
    float bb = bias[cb0 + nh + j * 16 + lm];
#pragma unroll
    for (int i = 0; i < 4; i++)
#pragma unroll
      for (int r = 0; r < 4; r++) acc[i][j][r] += bb;
  }

  __syncthreads();
  if (t < 128) { sredArr[t] = 0.f; qredArr[t] = 0.f; }
  __syncthreads();

#pragma unroll
  for (int j = 0; j < 4; j++) {
    float s = 0.f, q = 0.f;
#pragma unroll
    for (int i = 0; i < 4; i++)
#pragma unroll
      for (int r = 0; r < 4; r++) {
        int grow = p0 + mh + i * 16 + lq * 4 + r;
        if (grow < nrows) { float v = acc[i][j][r]; s += v; q += v * v; }
      }
    s += __shfl_xor(s, 16); s += __shfl_xor(s, 32);
    q += __shfl_xor(q, 16); q += __shfl_xor(q, 32);
    if (lq == 0) {
      atomicAdd(&sredArr[nh + j * 16 + lm], s);
      atomicAdd(&qredArr[nh + j * 16 + lm], q);
    }
  }

  for (int half = 0; half < 2; half++) {
    __syncthreads();
    if ((wv & 1) == half) {
#pragma unroll
      for (int j = 0; j < 4; j++)
#pragma unroll
        for (int i = 0; i < 4; i++)
#pragma unroll
          for (int r = 0; r < 4; r++)
            hA[(mh + i * 16 + lq * 4 + r) * LDO + j * 16 + lm] = __float2bfloat16(acc[i][j][r]);
    }
    __syncthreads();
    int row = t >> 1, seg = t & 1;
    int gp = p0 + row;
    if (gp < nrows) {
      size_t drow = perm ? (size_t)perm[gp] : (size_t)gp;
      const uint4* src = (const uint4*)&hA[row * LDO + seg * 32];
      uint4* dst = (uint4*)(Yout + drow * C + cb0 + half * 64 + seg * 32);
      dst[0] = src[0]; dst[1] = src[1]; dst[2] = src[2]; dst[3] = src[3];
    }
  }

  if (t < 128) {
    atomicAdd(&sums[cb0 + t], sredArr[t]);
    atomicAdd(&sums[C + cb0 + t], qredArr[t]);
  }
}

// ---- counting sort (batched over blockIdx.y) ----
__global__ __launch_bounds__(256) void hist_kernel(const int* __restrict__ gi, int perB,
                                                   unsigned* __restrict__ hist) {
  int b = blockIdx.y;
  int p = blockIdx.x * 256 + threadIdx.x;
  if (p < perB) {
    int gp = b * perB + p;
    int c = (gi[2 * gp] & 255) * 256 + (gi[2 * gp + 1] & 255);
    atomicAdd(&hist[b * 65536 + c], 1u);
  }
}
__global__ __launch_bounds__(256) void scan1(const unsigned* __restrict__ hist,
                                             unsigned* __restrict__ cursor,
                                             unsigned* __restrict__ bSums) {
  __shared__ unsigned s[256];
  int b = blockIdx.y;
  int t = threadIdx.x, i = b * 65536 + blockIdx.x * 256 + t;
  unsigned v = hist[i]; s[t] = v; __syncthreads();
  for (int off = 1; off < 256; off <<= 1) {
    unsigned x = (t >= off) ? s[t - off] : 0u; __syncthreads();
    s[t] += x; __syncthreads();
  }
  cursor[i] = s[t] - v;
  if (t == 255) bSums[b * 256 + blockIdx.x] = s[255];
}
__global__ void scan2(unsigned* __restrict__ bSums) {  // grid = 2 blocks (one per batch)
  __shared__ unsigned s[256];
  int t = threadIdx.x, i = blockIdx.x * 256 + t;
  unsigned v = bSums[i]; s[t] = v; __syncthreads();
  for (int off = 1; off < 256; off <<= 1) {
    unsigned x = (t >= off) ? s[t - off] : 0u; __syncthreads();
    s[t] += x; __syncthreads();
  }
  bSums[i] = s[t] - v;
}
// starts[b][c] = global exclusive prefix; starts[b][65536] = perB  (runs BEFORE scatter)
__global__ __launch_bounds__(256) void mk_starts(const unsigned* __restrict__ cursor,
                                                 const unsigned* __restrict__ bSums,
                                                 unsigned* __restrict__ starts, int perB) {
  int b = blockIdx.y;
  int i = blockIdx.x * 256 + threadIdx.x;
  starts[b * 65537 + i] = cursor[b * 65536 + i] + bSums[b * 256 + (i >> 8)];
  if (i == 0) starts[b * 65537 + 65536] = (unsigned)perB;
}
// scatter: cells[sorted position] = cell id; invPos[point] = global sorted row.
__global__ __launch_bounds__(256) void scatter_kernel(const int* __restrict__ gi, int perB,
                                                      unsigned* __restrict__ cursor,
                                                      const unsigned* __restrict__ bSums,
                                                      unsigned* __restrict__ cells,
                                                      unsigned* __restrict__ invPos) {
  int b = blockIdx.y;
  int p = blockIdx.x * 256 + threadIdx.x;
  if (p < perB) {
    int gp = b * perB + p;
    int c = (gi[2 * gp] & 255) * 256 + (gi[2 * gp + 1] & 255);
    unsigned pos = atomicAdd(&cursor[b * 65536 + c], 1u) + bSums[b * 256 + (c >> 8)];
    if (pos >= (unsigned)perB) pos = (unsigned)perB - 1u;  // fault insurance: never triggers
    cells[b * perB + pos] = (unsigned)c;
    invPos[gp] = (unsigned)(b * perB) + pos;
  }
}

// ---- fused stage-4 (r15/r17 proven body; compress tail spread to 4 waves):
// 32 exclusive cells, M=64, 256 thr, LDS 76.8 KB, (256,2). Y3 sorted ->
// contiguous staging; run-merged atomics (consecutive sorted rows share a cell,
// avg run 1.83: fold same-cell neighbors in-register, one atomic per run).
// Main rg loop byte-identical to r15 (r16 lesson: reshaping it spills). Tail
// change only: compress now uses all 4 waves -- wave wv owns (cellG=(wv&1)*16,
// colG=(wv>>1)*16) with a SINGLE accC (r5's proven mapping; fewer regs). ----
__global__ __launch_bounds__(256, 2) void pool_compress(
    const __hip_bfloat16* __restrict__ Y3, const __hip_bfloat16* __restrict__ Wt4,
    const float* __restrict__ b4, const float* __restrict__ sc, const float* __restrict__ sh,
    const __hip_bfloat16* __restrict__ WcT, const float* __restrict__ bc,
    const unsigned* __restrict__ sortedCell, const unsigned* __restrict__ startsAll,
    float* __restrict__ comp, int perB) {
  constexpr int K = 256, KS = 64, LDA = 72, MLW = 516;
  __shared__ __align__(16) __hip_bfloat16 hA[64 * LDA];   // 9.2 KB
  __shared__ __align__(16) unsigned maxLds[32 * MLW];     // 66.0 KB
  __shared__ unsigned char slotRow[256];
  const int t = threadIdx.x;
  const int lane = t & 63, wv = t >> 6;  // wave grid 1M x 4N: wave wv owns cols [wv*128, +128)
  const int lm = lane & 15, lq = lane >> 4;
  const int batch = blockIdx.y;
  const unsigned* starts = startsAll + batch * 65537;
  const int c0 = blockIdx.x * 32;
  const int r0 = (int)starts[c0];
  int n = (int)starts[c0 + 32] - r0;
  if (n > 256) n = 256;  // safety clamp (32 cells, ~59 pts avg: never hit)
  if (n < 0) n = 0;
  const int nrg = (n + 63) >> 6;
  const size_t rowBase = (size_t)batch * perB + r0;

  for (int i = t; i < n; i += 256)
    slotRow[i] = (unsigned char)((sortedCell[batch * perB + r0 + i] - c0) & 31);
  {
    const uint4 z4 = {0u, 0u, 0u, 0u};
    for (int i = t * 4; i < 32 * MLW; i += 1024) *(uint4*)&maxLds[i] = z4;
  }

  for (int rg = 0; rg < nrg; rg++) {
    const int rbase = rg * 64;
    f32x4 acc[4][8];
#pragma unroll
    for (int i = 0; i < 4; i++)
#pragma unroll
      for (int j = 0; j < 8; j++) acc[i][j] = {0.f, 0.f, 0.f, 0.f};
    for (int k0 = 0; k0 < K; k0 += KS) {
      __syncthreads();  // hA free (covers init/zeroing on first pass, prior reads after)
#pragma unroll
      for (int it = 0; it < 2; it++) {
        int idx = it * 256 + t;
        int row = idx >> 3;
        int c8 = (idx & 7) * 8;
        int gr = rbase + row;
        __hip_bfloat16 h8[8];
        if (gr < n) {
          uint4 raw = *(const uint4*)(Y3 + (rowBase + gr) * K + k0 + c8);
          const __hip_bfloat16* pr = (const __hip_bfloat16*)&raw;
#pragma unroll
          for (int j = 0; j < 8; j++) {
            float v = sc[k0 + c8 + j] * __bfloat162float(pr[j]) + sh[k0 + c8 + j];
            h8[j] = __float2bfloat16(fmaxf(v, 0.f));
          }
        } else {
#pragma unroll
          for (int j = 0; j < 8; j++) h8[j] = __float2bfloat16(0.f);
        }
        *(uint4*)&hA[row * LDA + c8] = *(const uint4*)h8;
      }
      __syncthreads();
#pragma unroll
      for (int kk = 0; kk < KS; kk += 32) {
        bf16x8 a[4];
#pragma unroll
        for (int i = 0; i < 4; i++)
          a[i] = *(const bf16x8*)&hA[(i * 16 + lm) * LDA + kk + lq * 8];
#pragma unroll
        for (int j = 0; j < 8; j++) {
          bf16x8 b = *(const bf16x8*)(const void*)(Wt4 + (size_t)(wv * 128 + j * 16 + lm) * K + k0 + kk + lq * 8);
#pragma unroll
          for (int i = 0; i < 4; i++)
            acc[i][j] = __builtin_amdgcn_mfma_f32_16x16x32_bf16(a[i], b, acc[i][j], 0, 0, 0);
        }
      }
    }
    // segmented max with run-merging (raw h4; bias folded at compress).
    // Rows of one f32x4 are consecutive -> fold same-cell neighbors in-register,
    // emit one atomic per run. Conditions uniform across j (hoisted).
#pragma unroll
    for (int i = 0; i < 4; i++) {
      const int base = rbase + i * 16 + lq * 4;
      const int rl = n - base;  // rows valid: r < rl
      if (rl <= 0) continue;
      const int s0 = slotRow[base];
      const int s1 = (rl > 1) ? (int)slotRow[base + 1] : -1;
      const int s2 = (rl > 2) ? (int)slotRow[base + 2] : -1;
      const int s3 = (rl > 3) ? (int)slotRow[base + 3] : -1;
      const bool m01 = (s1 == s0), m12 = (s2 == s1), m23 = (s3 == s2);
#pragma unroll
      for (int j = 0; j < 8; j++) {
        const int col = wv * 128 + j * 16 + lm;
        float v0 = acc[i][j][0], v1 = acc[i][j][1], v2 = acc[i][j][2], v3 = acc[i][j][3];
        v1 = m01 ? fmaxf(v1, v0) : v1;
        v2 = m12 ? fmaxf(v2, v1) : v2;
        v3 = m23 ? fmaxf(v3, v2) : v3;
        if (!m01)           atomicMax(&maxLds[s0 * MLW + col], encf(v0));
        if (rl > 1 && !m12) atomicMax(&maxLds[s1 * MLW + col], encf(v1));
        if (rl > 2 && !m23) atomicMax(&maxLds[s2 * MLW + col], encf(v2));
        if (rl > 3)         atomicMax(&maxLds[s3 * MLW + col], encf(v3));
      }
    }
  }
  __syncthreads();  // all segmax atomics complete

  // compress: all 4 waves. Wave wv owns cells [cellG, +16) x output cols
  // [colG, +16); single pass over all 512 k-cols, single accC per thread.
  {
    const int cellG = (wv & 1) * 16, colG = (wv >> 1) * 16;
    f32x4 accC = {0.f, 0.f, 0.f, 0.f};
#pragma unroll
    for (int ks = 0; ks < 16; ks++) {
      int koff = ks * 32 + lq * 8;
      const unsigned* mp = &maxLds[(cellG + lm) * MLW + koff];
      uint4 m0 = *(const uint4*)mp;
      uint4 m1 = *(const uint4*)(mp + 4);
      unsigned mu[8] = {m0.x, m0.y, m0.z, m0.w, m1.x, m1.y, m1.z, m1.w};
      __hip_bfloat16 af[8];
#pragma unroll
      for (int j = 0; j < 8; j++)
        af[j] = __float2bfloat16(decf(mu[j]) + b4[koff + j]);
      bf16x8 aa = *(const bf16x8*)af;
      bf16x8 b = *(const bf16x8*)(const void*)(WcT + (size_t)(colG + lm) * 512 + koff);
      accC = __builtin_amdgcn_mfma_f32_16x16x32_bf16(aa, b, accC, 0, 0, 0);
    }
    // write: cell = c0 + cellG + lq*4 + r, col = colG + lm. Empty cells: NaN from
    // decf(0) poisons accC rows -> masked by occ to exact 0.
    float bb = bc[colG + lm];
#pragma unroll
    for (int r = 0; r < 4; r++) {
      int cell = c0 + cellG + lq * 4 + r;
      int occ = starts[cell + 1] > starts[cell];
      float v = occ ? fmaxf(accC[r] + bb, 0.f) : 0.f;
      comp[((size_t)batch * 65536 + cell) * 32 + colG + lm] = v;
    }
  }
}

// ---- fused epilogue: blocks [0,2048) = separable 3x3 maxpool into channels
// 32..63 (x-dir max -> LDS, then z-dir max: 3+3 reads instead of 9);
// blocks [2048, 6144) = occupancy transpose (float4) into channels 0..31. ----
__global__ __launch_bounds__(256) void epilogue_write(const float* __restrict__ comp,
                                                      const float* __restrict__ occ,
                                                      float* __restrict__ out) {
  int bid = blockIdx.x;
  if (bid < 2048) {
    __shared__ float tile[32][73];  // 66 used slots (+halo), padded stride
    int z0 = (bid & 3) * 64, x = (bid >> 2) & 255, b = bid >> 10;
    int f = threadIdx.x & 31, zs = threadIdx.x >> 5;
    // phase 1: x-direction max for z slots [z0-1, z0+64], slot = z - z0 + 1
    for (int zi = 0; zi < 9; zi++) {
      int slot = zi * 8 + zs;
      if (slot >= 66) break;
      int z = z0 + slot - 1;
      float m = -3.402823466e38f;
      if (z >= 0 && z <= 255) {
        for (int dx = -1; dx <= 1; dx++) {
          int xx = x + dx;
          if (xx < 0 || xx > 255) continue;
          m = fmaxf(m, comp[(size_t)((b << 16) + (xx << 8) + z) * 32 + f]);
        }
      }
      tile[f][slot] = m;
    }
    __syncthreads();
    // phase 2: z-direction max + transpose write (full 32B lines per thread)
    int f2 = threadIdx.x >> 3, seg = threadIdx.x & 7;
    float* dst = out + ((size_t)(b * 64 + 32 + f2) * 256 + x) * 256 + z0 + seg * 8;
#pragma unroll
    for (int u = 0; u < 8; u++) {
      int s = seg * 8 + u;
      dst[u] = fmaxf(fmaxf(tile[f2][s], tile[f2][s + 1]), tile[f2][s + 2]);
    }
  } else {
    int oidx = (bid - 2048) * 256 + threadIdx.x;  // 4096*256 = 1,048,576 threads
    int z4 = oidx & 63, x = (oidx >> 6) & 255, hh = (oidx >> 14) & 31, b = oidx >> 19;
    const float4 v = *(const float4*)(occ + ((((size_t)b * 256 + x) * 32 + hh) * 256 + z4 * 4));
    *(float4*)(out + (((size_t)(b * 64 + hh) * 256 + x) * 256 + z4 * 4)) = v;
  }
}

extern "C" void kernel_launch(void* const* d_in, const int* in_sizes, int n_in,
                              void* d_out, int out_size, void* d_ws, size_t ws_size,
                              hipStream_t stream) {
  const float* pt_fea   = (const float*)d_in[0];
  const int*   grid_ind = (const int*)d_in[1];
  const float* occup    = (const float*)d_in[2];
  const float* W1 = (const float*)d_in[3];  const float* b1 = (const float*)d_in[4];
  const float* W2 = (const float*)d_in[5];  const float* b2 = (const float*)d_in[6];
  const float* W3 = (const float*)d_in[7];  const float* b3 = (const float*)d_in[8];
  const float* W4 = (const float*)d_in[9];  const float* b4 = (const float*)d_in[10];
  const float* g0 = (const float*)d_in[11]; const float* be0 = (const float*)d_in[12];
  const float* g1 = (const float*)d_in[13]; const float* be1 = (const float*)d_in[14];
  const float* g2 = (const float*)d_in[15]; const float* be2 = (const float*)d_in[16];
  const float* g3 = (const float*)d_in[17]; const float* be3 = (const float*)d_in[18];
  const float* Wc = (const float*)d_in[19]; const float* bc = (const float*)d_in[20];
  float* out = (float*)d_out;

  const int nPts = in_sizes[0] / 3;  // 240000
  const int perB = nPts / 2;         // 120000
  const float invN = 1.f / (float)nPts;

  // ---- workspace layout, peak ~215.4 MB ----
  char* ws = (char*)d_ws;
  float* stats = (float*)ws;
  float* scsh  = (float*)(ws + 4096);
  float* sums0 = stats;        float* sums1 = stats + 16;
  float* sums2 = stats + 160;  float* sums3 = stats + 416;
  float* sc0 = scsh;
  float* sc1 = scsh + 16;   float* sh1 = scsh + 80;
  float* sc2 = scsh + 144;  float* sh2 = scsh + 272;
  float* sc3 = scsh + 400;  float* sh3 = scsh + 656;
  __hip_bfloat16* Wt2 = (__hip_bfloat16*)(ws + 8192);     // 16 KB
  __hip_bfloat16* Wt3 = (__hip_bfloat16*)(ws + 24576);    // 64 KB
  __hip_bfloat16* Wt4 = (__hip_bfloat16*)(ws + 90112);    // 256 KB
  __hip_bfloat16* WcT = (__hip_bfloat16*)(ws + 352256);   // 32 KB -> ends 385024
  char* S0 = ws + 385024;
  __hip_bfloat16* Y1 = (__hip_bfloat16*)S0;                    // 30.72 MB
  __hip_bfloat16* Y2 = (__hip_bfloat16*)(S0 + 30720000ll);     // 61.44 MB
  __hip_bfloat16* Y3 = (__hip_bfloat16*)(S0 + 92160000ll);     // 122.88 MB
  // stage-4 aliases over dead Y1 (sort region written only AFTER stage 2 in
  // stream order; comp written only by pool_compress):
  float* comp       = (float*)S0;                              // 16.78 MB
  char* sortBase    = S0 + 17000000ll;                         // inside Y1, after comp
  unsigned* hist    = (unsigned*)sortBase;                     // 2*65536   (512 KB)
  unsigned* cursor  = hist + 2 * 65536;                        // 2*65536   (512 KB)
  unsigned* bSums   = cursor + 2 * 65536;                      // 2*256 (pad 1024)
  unsigned* startsA = bSums + 1024;                            // 2*65537 (pad 131080)
  unsigned* cells   = startsA + 131080;                        // 2*perB    (960 KB)
  unsigned* invPos  = cells + 2 * perB;                        // 2*perB    (960 KB)
  // sort region ends ~S0+20.5 MB < Y1 end (30.72 MB): never touches Y2/Y3.

  hipMemsetAsync(stats, 0, 4096, stream);

  wconv4<<<736, 256, 0, stream>>>(W2, W3, W4, Wc, Wt2, Wt3, Wt4, WcT);

  // stage 0
  stats_feats<<<256, 256, 0, stream>>>(pt_fea, nPts, sums0);
  bn_prep<<<1, 256, 0, stream>>>(sums0, 3, invN, g0, be0, sc0, scsh + 4);

  // stage 1 (fused stats)
  gemm1_stats<<<512, 256, 0, stream>>>(pt_fea, W1, b1, scsh, Y1, nPts, sums1);
  bn_prep<<<1, 256, 0, stream>>>(sums1, 64, invN, g1, be1, sc1, sh1);

  // stage 2 (MFMA, fused stats)
  gemm_mfma<64><<<dim3(nPts / 128, 1), 256, 0, stream>>>(Y1, Wt2, b2, sc1, sh1, Y2, 128, sums2, nPts, nullptr);
  bn_prep<<<1, 256, 0, stream>>>(sums2, 128, invN, g2, be2, sc2, sh2);

  // counting sort BEFORE stage 3 (needs only grid_ind; sort region aliases Y1,
  // which is dead after stage 2 -- memset must come AFTER stage-2 enqueue).
  hipMemsetAsync(hist, 0, 2 * 65536 * 4, stream);
  const int pgrid = (perB + 255) / 256;
  hist_kernel<<<dim3(pgrid, 2), 256, 0, stream>>>(grid_ind, perB, hist);
  scan1<<<dim3(256, 2), 256, 0, stream>>>(hist, cursor, bSums);
  scan2<<<2, 256, 0, stream>>>(bSums);
  mk_starts<<<dim3(256, 2), 256, 0, stream>>>(cursor, bSums, startsA, perB);
  scatter_kernel<<<dim3(pgrid, 2), 256, 0, stream>>>(grid_ind, perB, cursor, bSums, cells, invPos);

  // stage 3 (MFMA, fused stats, PERMUTED write: Y3 lands in sorted order)
  gemm_mfma<128><<<dim3(nPts / 128, 2), 256, 0, stream>>>(Y2, Wt3, b3, sc2, sh2, Y3, 256, sums3, nPts, invPos);
  bn_prep<<<1, 256, 0, stream>>>(sums3, 256, invN, g3, be3, sc3, sh3);

  // fused stage-4: pool + compress, contiguous Y3 reads, run-merged atomics,
  // 4-wave compress. 32 cells/block -> (2048, 2).
  pool_compress<<<dim3(2048, 2), 256, 0, stream>>>(
      Y3, Wt4, b4, sc3, sh3, WcT, bc, cells, startsA, comp, perB);

  // fused epilogue: separable maxpool (2048 blocks) + occupancy transpose (4096 blocks)
  epilogue_write<<<6144, 256, 0, stream>>>(comp, occup, out);
}

// Round 19
// 688.803 us; speedup vs baseline: 1.3071x; 1.0140x over previous
//
#include <hip/hip_runtime.h>
#include <hip/hip_bf16.h>

#define EPSN 1e-5f

typedef __bf16 bf16x8 __attribute__((ext_vector_type(8)));
typedef float f32x4 __attribute__((ext_vector_type(4)));

// ---- order-preserving float<->uint encoding for max pooling ----
// enc sentinel 0u decodes to NaN -> poisons only empty-cell rows, masked at write.
__device__ __forceinline__ unsigned encf(float f) {
  unsigned u = __float_as_uint(f);
  return (u & 0x80000000u) ? ~u : (u | 0x80000000u);
}
__device__ __forceinline__ float decf(unsigned u) {
  return (u & 0x80000000u) ? __uint_as_float(u ^ 0x80000000u) : __uint_as_float(~u);
}

// ---- column stats (sum, sumsq) of the raw 3-feature input ----
__global__ __launch_bounds__(256) void stats_feats(const float* __restrict__ pt, int n,
                                                   float* __restrict__ sums) {
  float a0 = 0, a1 = 0, a2 = 0, q0 = 0, q1 = 0, q2 = 0;
  for (int p = blockIdx.x * 256 + threadIdx.x; p < n; p += gridDim.x * 256) {
    float v0 = pt[3 * p], v1 = pt[3 * p + 1], v2 = pt[3 * p + 2];
    a0 += v0; a1 += v1; a2 += v2;
    q0 += v0 * v0; q1 += v1 * v1; q2 += v2 * v2;
  }
  __shared__ float red[4][6];
  float vals[6] = {a0, a1, a2, q0, q1, q2};
  int lane = threadIdx.x & 63, wv = threadIdx.x >> 6;
#pragma unroll
  for (int k = 0; k < 6; k++) {
    float v = vals[k];
#pragma unroll
    for (int o = 32; o; o >>= 1) v += __shfl_down(v, o, 64);
    if (lane == 0) red[wv][k] = v;
  }
  __syncthreads();
  if (threadIdx.x < 6) {
    float v = red[0][threadIdx.x] + red[1][threadIdx.x] + red[2][threadIdx.x] + red[3][threadIdx.x];
    atomicAdd(&sums[threadIdx.x], v);
  }
}

// ---- fold BN (train-mode batch stats) + affine into per-column scale/shift ----
__global__ void bn_prep(const float* __restrict__ sums, int C, float invN,
                        const float* __restrict__ g, const float* __restrict__ be,
                        float* __restrict__ sc, float* __restrict__ sh) {
  int c = threadIdx.x;
  if (c < C) {
    float m = sums[c] * invN;
    float v = fmaxf(sums[C + c] * invN - m * m, 0.f);
    float s = g[c] * rsqrtf(v + EPSN);
    sc[c] = s;
    sh[c] = be[c] - m * s;
  }
}

// ---- fused weight conversions: fp32 W[K][C] -> bf16 Wt[C][K] for all 4 weights ----
__global__ __launch_bounds__(256) void wconv4(
    const float* __restrict__ W2, const float* __restrict__ W3,
    const float* __restrict__ W4, const float* __restrict__ Wc,
    __hip_bfloat16* __restrict__ Wt2, __hip_bfloat16* __restrict__ Wt3,
    __hip_bfloat16* __restrict__ Wt4, __hip_bfloat16* __restrict__ WcT) {
  int idx = blockIdx.x * 256 + threadIdx.x;
  const float* W; __hip_bfloat16* Wt; int K, C, l;
  if (idx < 8192)        { W = W2; Wt = Wt2; K = 64;  C = 128; l = idx; }
  else if (idx < 40960)  { W = W3; Wt = Wt3; K = 128; C = 256; l = idx - 8192; }
  else if (idx < 172032) { W = W4; Wt = Wt4; K = 256; C = 512; l = idx - 40960; }
  else if (idx < 188416) { W = Wc; Wt = WcT; K = 512; C = 32;  l = idx - 172032; }
  else return;
  int k = l / C, c = l - k * C;
  Wt[(size_t)c * K + k] = __float2bfloat16(W[l]);
}

// ---- stage 1 fused: Y1 = BN(feats)@W1 + b1, column stats inline ----
__global__ __launch_bounds__(256) void gemm1_stats(const float* __restrict__ pt,
                                                   const float* __restrict__ W,
                                                   const float* __restrict__ bias,
                                                   const float* __restrict__ scsh,
                                                   __hip_bfloat16* __restrict__ Y,
                                                   int n, float* __restrict__ sums) {
  const int c = threadIdx.x & 63;
  const float w0 = W[c], w1 = W[64 + c], w2 = W[128 + c], bb = bias[c];
  const float s0 = scsh[0], s1 = scsh[1], s2 = scsh[2];
  const float h0 = scsh[4], h1 = scsh[5], h2 = scsh[6];
  float s = 0.f, q = 0.f;
  const int total = n * 64;
  for (int idx = blockIdx.x * 256 + threadIdx.x; idx < total; idx += gridDim.x * 256) {
    int p = idx >> 6;
    float x0 = s0 * pt[3 * p]     + h0;
    float x1 = s1 * pt[3 * p + 1] + h1;
    float x2 = s2 * pt[3 * p + 2] + h2;
    float y = bb + x0 * w0 + x1 * w1 + x2 * w2;
    Y[idx] = __float2bfloat16(y);
    s += y; q += y * y;
  }
  __shared__ float sred[4][64], qred[4][64];
  int wv = threadIdx.x >> 6;
  sred[wv][c] = s; qred[wv][c] = q;
  __syncthreads();
  if (threadIdx.x < 64) {
    float S = sred[0][c] + sred[1][c] + sred[2][c] + sred[3][c];
    float Q = qred[0][c] + qred[1][c] + qred[2][c] + qred[3][c];
    atomicAdd(&sums[c], S);
    atomicAdd(&sums[64 + c], Q);
  }
}

// ---- MFMA GEMM (stages 2/3): Yout = relu(sc*Yin+sh)@W + bias, fused column stats.
// Output staged through LDS, contiguous 64B/lane stores. Optional perm: output
// row i lands at row perm[i] (stage 3 writes Y3 in SORTED order so stage 4 reads
// are contiguous -- write-side scatter is fire-and-forget). ----
template <int K>
__global__ __launch_bounds__(256) void gemm_mfma(
    const __hip_bfloat16* __restrict__ Yin, const __hip_bfloat16* __restrict__ Wt,
    const float* __restrict__ bias, const float* __restrict__ sc, const float* __restrict__ sh,
    __hip_bfloat16* __restrict__ Yout, int C, float* __restrict__ sums, int nrows,
    const unsigned* __restrict__ perm) {
  constexpr int KS = 64, LDA = 72, LDO = 80;
  __shared__ __align__(16) __hip_bfloat16 hA[128 * LDO];
  __shared__ float sredArr[128], qredArr[128];
  const int t = threadIdx.x;
  const int lane = t & 63, wv = t >> 6;
  const int mh = (wv >> 1) * 64, nh = (wv & 1) * 64;
  const int lm = lane & 15, lq = lane >> 4;
  const int p0 = blockIdx.x * 128;
  const int cb0 = blockIdx.y * 128;

  f32x4 acc[4][4];
#pragma unroll
  for (int i = 0; i < 4; i++)
#pragma unroll
    for (int j = 0; j < 4; j++) acc[i][j] = {0.f, 0.f, 0.f, 0.f};

  for (int k0 = 0; k0 < K; k0 += KS) {
    __syncthreads();
#pragma unroll
    for (int it = 0; it < 4; it++) {
      int idx = it * 256 + t;
      int row = idx >> 3;
      int c8 = (idx & 7) * 8;
      int gp = p0 + row;
      __hip_bfloat16 h8[8];
      if (gp < nrows) {
        uint4 raw = *(const uint4*)(Yin + (size_t)gp * K + k0 + c8);
        const __hip_bfloat16* pr = (const __hip_bfloat16*)&raw;
#pragma unroll
        for (int j = 0; j < 8; j++) {
          float v = sc[k0 + c8 + j] * __bfloat162float(pr[j]) + sh[k0 + c8 + j];
          h8[j] = __float2bfloat16(fmaxf(v, 0.f));
        }
      } else {
#pragma unroll
        for (int j = 0; j < 8; j++) h8[j] = __float2bfloat16(0.f);
      }
      *(uint4*)&hA[row * LDA + c8] = *(const uint4*)h8;
    }
    __syncthreads();
#pragma unroll
    for (int kk = 0; kk < KS; kk += 32) {
      bf16x8 a[4], b[4];
#pragma unroll
      for (int i = 0; i < 4; i++)
        a[i] = *(const bf16x8*)&hA[(mh + i * 16 + lm) * LDA + kk + lq * 8];
#pragma unroll
      for (int j = 0; j < 4; j++)
        b[j] = *(const bf16x8*)(const void*)(Wt + (size_t)(cb0 + nh + j * 16 + lm) * K + k0 + kk + lq * 8);
#pragma unroll
      for (int i = 0; i < 4; i++)
#pragma unroll
        for (int j = 0; j < 4; j++)
          acc[i][j] = __builtin_amdgcn_mfma_f32_16x16x32_bf16(a[i], b[j], acc[i][j], 0, 0, 0);
    }
  }

#pragma unroll
  for (int j = 0; j < 4; j++) {
    float bb = bias[cb0 + nh + j * 16 + lm];
#pragma unroll
    for (int i = 0; i < 4; i++)
#pragma unroll
      for (int r = 0; r < 4; r++) acc[i][j][r] += bb;
  }

  __syncthreads();
  if (t < 128) { sredArr[t] = 0.f; qredArr[t] = 0.f; }
  __syncthreads();

#pragma unroll
  for (int j = 0; j < 4; j++) {
    float s = 0.f, q = 0.f;
#pragma unroll
    for (int i = 0; i < 4; i++)
#pragma unroll
      for (int r = 0; r < 4; r++) {
        int grow = p0 + mh + i * 16 + lq * 4 + r;
        if (grow < nrows) { float v = acc[i][j][r]; s += v; q += v * v; }
      }
    s += __shfl_xor(s, 16); s += __shfl_xor(s, 32);
    q += __shfl_xor(q, 16); q += __shfl_xor(q, 32);
    if (lq == 0) {
      atomicAdd(&sredArr[nh + j * 16 + lm], s);
      atomicAdd(&qredArr[nh + j * 16 + lm], q);
    }
  }

  for (int half = 0; half < 2; half++) {
    __syncthreads();
    if ((wv & 1) == half) {
#pragma unroll
      for (int j = 0; j < 4; j++)
#pragma unroll
        for (int i = 0; i < 4; i++)
#pragma unroll
          for (int r = 0; r < 4; r++)
            hA[(mh + i * 16 + lq * 4 + r) * LDO + j * 16 + lm] = __float2bfloat16(acc[i][j][r]);
    }
    __syncthreads();
    int row = t >> 1, seg = t & 1;
    int gp = p0 + row;
    if (gp < nrows) {
      size_t drow = perm ? (size_t)perm[gp] : (size_t)gp;
      const uint4* src = (const uint4*)&hA[row * LDO + seg * 32];
      uint4* dst = (uint4*)(Yout + drow * C + cb0 + half * 64 + seg * 32);
      dst[0] = src[0]; dst[1] = src[1]; dst[2] = src[2]; dst[3] = src[3];
    }
  }

  if (t < 128) {
    atomicAdd(&sums[cb0 + t], sredArr[t]);
    atomicAdd(&sums[C + cb0 + t], qredArr[t]);
  }
}

// ---- counting sort (batched over blockIdx.y) ----
__global__ __launch_bounds__(256) void hist_kernel(const int* __restrict__ gi, int perB,
                                                   unsigned* __restrict__ hist) {
  int b = blockIdx.y;
  int p = blockIdx.x * 256 + threadIdx.x;
  if (p < perB) {
    int gp = b * perB + p;
    int c = (gi[2 * gp] & 255) * 256 + (gi[2 * gp + 1] & 255);
    atomicAdd(&hist[b * 65536 + c], 1u);
  }
}
__global__ __launch_bounds__(256) void scan1(const unsigned* __restrict__ hist,
                                             unsigned* __restrict__ cursor,
                                             unsigned* __restrict__ bSums) {
  __shared__ unsigned s[256];
  int b = blockIdx.y;
  int t = threadIdx.x, i = b * 65536 + blockIdx.x * 256 + t;
  unsigned v = hist[i]; s[t] = v; __syncthreads();
  for (int off = 1; off < 256; off <<= 1) {
    unsigned x = (t >= off) ? s[t - off] : 0u; __syncthreads();
    s[t] += x; __syncthreads();
  }
  cursor[i] = s[t] - v;
  if (t == 255) bSums[b * 256 + blockIdx.x] = s[255];
}
__global__ void scan2(unsigned* __restrict__ bSums) {  // grid = 2 blocks (one per batch)
  __shared__ unsigned s[256];
  int t = threadIdx.x, i = blockIdx.x * 256 + t;
  unsigned v = bSums[i]; s[t] = v; __syncthreads();
  for (int off = 1; off < 256; off <<= 1) {
    unsigned x = (t >= off) ? s[t - off] : 0u; __syncthreads();
    s[t] += x; __syncthreads();
  }
  bSums[i] = s[t] - v;
}
// starts[b][c] = global exclusive prefix; starts[b][65536] = perB  (runs BEFORE scatter)
__global__ __launch_bounds__(256) void mk_starts(const unsigned* __restrict__ cursor,
                                                 const unsigned* __restrict__ bSums,
                                                 unsigned* __restrict__ starts, int perB) {
  int b = blockIdx.y;
  int i = blockIdx.x * 256 + threadIdx.x;
  starts[b * 65537 + i] = cursor[b * 65536 + i] + bSums[b * 256 + (i >> 8)];
  if (i == 0) starts[b * 65537 + 65536] = (unsigned)perB;
}
// scatter: cells[sorted position] = cell id; invPos[point] = global sorted row.
__global__ __launch_bounds__(256) void scatter_kernel(const int* __restrict__ gi, int perB,
                                                      unsigned* __restrict__ cursor,
                                                      const unsigned* __restrict__ bSums,
                                                      unsigned* __restrict__ cells,
                                                      unsigned* __restrict__ invPos) {
  int b = blockIdx.y;
  int p = blockIdx.x * 256 + threadIdx.x;
  if (p < perB) {
    int gp = b * perB + p;
    int c = (gi[2 * gp] & 255) * 256 + (gi[2 * gp + 1] & 255);
    unsigned pos = atomicAdd(&cursor[b * 65536 + c], 1u) + bSums[b * 256 + (c >> 8)];
    if (pos >= (unsigned)perB) pos = (unsigned)perB - 1u;  // fault insurance: never triggers
    cells[b * perB + pos] = (unsigned)c;
    invPos[gp] = (unsigned)(b * perB) + pos;
  }
}

// ---- fused stage-4 (EXACT r15/r17 body -- proven 290-313us, 116 VGPR, zero
// spill): 32 exclusive cells, M=64, 256 thr, LDS 76.8 KB, (256,2). Y3 sorted ->
// contiguous staging; run-merged atomics (consecutive sorted rows share a cell,
// avg run 1.83: fold same-cell neighbors in-register, one atomic per run).
// r18's 4-wave compress regressed (bank conflicts 4.95M->6.0M, +12us) ->
// reverted to the 2-wave accC[2] tail. r16 lesson holds: never reshape the rg
// body. This is the final composed-best configuration. ----
__global__ __launch_bounds__(256, 2) void pool_compress(
    const __hip_bfloat16* __restrict__ Y3, const __hip_bfloat16* __restrict__ Wt4,
    const float* __restrict__ b4, const float* __restrict__ sc, const float* __restrict__ sh,
    const __hip_bfloat16* __restrict__ WcT, const float* __restrict__ bc,
    const unsigned* __restrict__ sortedCell, const unsigned* __restrict__ startsAll,
    float* __restrict__ comp, int perB) {
  constexpr int K = 256, KS = 64, LDA = 72, MLW = 516;
  __shared__ __align__(16) __hip_bfloat16 hA[64 * LDA];   // 9.2 KB
  __shared__ __align__(16) unsigned maxLds[32 * MLW];     // 66.0 KB
  __shared__ unsigned char slotRow[256];
  const int t = threadIdx.x;
  const int lane = t & 63, wv = t >> 6;  // wave grid 1M x 4N: wave wv owns cols [wv*128, +128)
  const int lm = lane & 15, lq = lane >> 4;
  const int batch = blockIdx.y;
  const unsigned* starts = startsAll + batch * 65537;
  const int c0 = blockIdx.x * 32;
  const int r0 = (int)starts[c0];
  int n = (int)starts[c0 + 32] - r0;
  if (n > 256) n = 256;  // safety clamp (32 cells, ~59 pts avg: never hit)
  if (n < 0) n = 0;
  const int nrg = (n + 63) >> 6;
  const size_t rowBase = (size_t)batch * perB + r0;

  for (int i = t; i < n; i += 256)
    slotRow[i] = (unsigned char)((sortedCell[batch * perB + r0 + i] - c0) & 31);
  {
    const uint4 z4 = {0u, 0u, 0u, 0u};
    for (int i = t * 4; i < 32 * MLW; i += 1024) *(uint4*)&maxLds[i] = z4;
  }

  for (int rg = 0; rg < nrg; rg++) {
    const int rbase = rg * 64;
    f32x4 acc[4][8];
#pragma unroll
    for (int i = 0; i < 4; i++)
#pragma unroll
      for (int j = 0; j < 8; j++) acc[i][j] = {0.f, 0.f, 0.f, 0.f};
    for (int k0 = 0; k0 < K; k0 += KS) {
      __syncthreads();  // hA free (covers init/zeroing on first pass, prior reads after)
#pragma unroll
      for (int it = 0; it < 2; it++) {
        int idx = it * 256 + t;
        int row = idx >> 3;
        int c8 = (idx & 7) * 8;
        int gr = rbase + row;
        __hip_bfloat16 h8[8];
        if (gr < n) {
          uint4 raw = *(const uint4*)(Y3 + (rowBase + gr) * K + k0 + c8);
          const __hip_bfloat16* pr = (const __hip_bfloat16*)&raw;
#pragma unroll
          for (int j = 0; j < 8; j++) {
            float v = sc[k0 + c8 + j] * __bfloat162float(pr[j]) + sh[k0 + c8 + j];
            h8[j] = __float2bfloat16(fmaxf(v, 0.f));
          }
        } else {
#pragma unroll
          for (int j = 0; j < 8; j++) h8[j] = __float2bfloat16(0.f);
        }
        *(uint4*)&hA[row * LDA + c8] = *(const uint4*)h8;
      }
      __syncthreads();
#pragma unroll
      for (int kk = 0; kk < KS; kk += 32) {
        bf16x8 a[4];
#pragma unroll
        for (int i = 0; i < 4; i++)
          a[i] = *(const bf16x8*)&hA[(i * 16 + lm) * LDA + kk + lq * 8];
#pragma unroll
        for (int j = 0; j < 8; j++) {
          bf16x8 b = *(const bf16x8*)(const void*)(Wt4 + (size_t)(wv * 128 + j * 16 + lm) * K + k0 + kk + lq * 8);
#pragma unroll
          for (int i = 0; i < 4; i++)
            acc[i][j] = __builtin_amdgcn_mfma_f32_16x16x32_bf16(a[i], b, acc[i][j], 0, 0, 0);
        }
      }
    }
    // segmented max with run-merging (raw h4; bias folded at compress).
    // Rows of one f32x4 are consecutive -> fold same-cell neighbors in-register,
    // emit one atomic per run. Conditions uniform across j (hoisted).
#pragma unroll
    for (int i = 0; i < 4; i++) {
      const int base = rbase + i * 16 + lq * 4;
      const int rl = n - base;  // rows valid: r < rl
      if (rl <= 0) continue;
      const int s0 = slotRow[base];
      const int s1 = (rl > 1) ? (int)slotRow[base + 1] : -1;
      const int s2 = (rl > 2) ? (int)slotRow[base + 2] : -1;
      const int s3 = (rl > 3) ? (int)slotRow[base + 3] : -1;
      const bool m01 = (s1 == s0), m12 = (s2 == s1), m23 = (s3 == s2);
#pragma unroll
      for (int j = 0; j < 8; j++) {
        const int col = wv * 128 + j * 16 + lm;
        float v0 = acc[i][j][0], v1 = acc[i][j][1], v2 = acc[i][j][2], v3 = acc[i][j][3];
        v1 = m01 ? fmaxf(v1, v0) : v1;
        v2 = m12 ? fmaxf(v2, v1) : v2;
        v3 = m23 ? fmaxf(v3, v2) : v3;
        if (!m01)           atomicMax(&maxLds[s0 * MLW + col], encf(v0));
        if (rl > 1 && !m12) atomicMax(&maxLds[s1 * MLW + col], encf(v1));
        if (rl > 2 && !m23) atomicMax(&maxLds[s2 * MLW + col], encf(v2));
        if (rl > 3)         atomicMax(&maxLds[s3 * MLW + col], encf(v3));
      }
    }
  }
  __syncthreads();  // all segmax atomics complete

  // compress: waves 0,1 own cells [wv*16, +16); single pass over all 512 k-cols.
  if (wv < 2) {
    f32x4 accC[2];
    accC[0] = {0.f, 0.f, 0.f, 0.f};
    accC[1] = {0.f, 0.f, 0.f, 0.f};
#pragma unroll
    for (int ks = 0; ks < 16; ks++) {
      int koff = ks * 32 + lq * 8;
      const unsigned* mp = &maxLds[(wv * 16 + lm) * MLW + koff];
      uint4 m0 = *(const uint4*)mp;
      uint4 m1 = *(const uint4*)(mp + 4);
      unsigned mu[8] = {m0.x, m0.y, m0.z, m0.w, m1.x, m1.y, m1.z, m1.w};
      __hip_bfloat16 af[8];
#pragma unroll
      for (int j = 0; j < 8; j++)
        af[j] = __float2bfloat16(decf(mu[j]) + b4[koff + j]);
      bf16x8 aa = *(const bf16x8*)af;
#pragma unroll
      for (int jn = 0; jn < 2; jn++) {
        bf16x8 b = *(const bf16x8*)(const void*)(WcT + (size_t)(jn * 16 + lm) * 512 + koff);
        accC[jn] = __builtin_amdgcn_mfma_f32_16x16x32_bf16(aa, b, accC[jn], 0, 0, 0);
      }
    }
    // final write: cell = c0 + wv*16 + lq*4 + r, col = jn*16+lm. Empty cells: NaN
    // from decf(0) poisons accC rows -> masked by occ to exact 0.
#pragma unroll
    for (int jn = 0; jn < 2; jn++) {
      float bb = bc[jn * 16 + lm];
#pragma unroll
      for (int r = 0; r < 4; r++) {
        int cell = c0 + wv * 16 + lq * 4 + r;
        int occ = starts[cell + 1] > starts[cell];
        float v = occ ? fmaxf(accC[jn][r] + bb, 0.f) : 0.f;
        comp[((size_t)batch * 65536 + cell) * 32 + jn * 16 + lm] = v;
      }
    }
  }
}

// ---- fused epilogue: blocks [0,2048) = separable 3x3 maxpool into channels
// 32..63 (x-dir max -> LDS, then z-dir max: 3+3 reads instead of 9);
// blocks [2048, 6144) = occupancy transpose (float4) into channels 0..31. ----
__global__ __launch_bounds__(256) void epilogue_write(const float* __restrict__ comp,
                                                      const float* __restrict__ occ,
                                                      float* __restrict__ out) {
  int bid = blockIdx.x;
  if (bid < 2048) {
    __shared__ float tile[32][73];  // 66 used slots (+halo), padded stride
    int z0 = (bid & 3) * 64, x = (bid >> 2) & 255, b = bid >> 10;
    int f = threadIdx.x & 31, zs = threadIdx.x >> 5;
    // phase 1: x-direction max for z slots [z0-1, z0+64], slot = z - z0 + 1
    for (int zi = 0; zi < 9; zi++) {
      int slot = zi * 8 + zs;
      if (slot >= 66) break;
      int z = z0 + slot - 1;
      float m = -3.402823466e38f;
      if (z >= 0 && z <= 255) {
        for (int dx = -1; dx <= 1; dx++) {
          int xx = x + dx;
          if (xx < 0 || xx > 255) continue;
          m = fmaxf(m, comp[(size_t)((b << 16) + (xx << 8) + z) * 32 + f]);
        }
      }
      tile[f][slot] = m;
    }
    __syncthreads();
    // phase 2: z-direction max + transpose write (full 32B lines per thread)
    int f2 = threadIdx.x >> 3, seg = threadIdx.x & 7;
    float* dst = out + ((size_t)(b * 64 + 32 + f2) * 256 + x) * 256 + z0 + seg * 8;
#pragma unroll
    for (int u = 0; u < 8; u++) {
      int s = seg * 8 + u;
      dst[u] = fmaxf(fmaxf(tile[f2][s], tile[f2][s + 1]), tile[f2][s + 2]);
    }
  } else {
    int oidx = (bid - 2048) * 256 + threadIdx.x;  // 4096*256 = 1,048,576 threads
    int z4 = oidx & 63, x = (oidx >> 6) & 255, hh = (oidx >> 14) & 31, b = oidx >> 19;
    const float4 v = *(const float4*)(occ + ((((size_t)b * 256 + x) * 32 + hh) * 256 + z4 * 4));
    *(float4*)(out + (((size_t)(b * 64 + hh) * 256 + x) * 256 + z4 * 4)) = v;
  }
}

extern "C" void kernel_launch(void* const* d_in, const int* in_sizes, int n_in,
                              void* d_out, int out_size, void* d_ws, size_t ws_size,
                              hipStream_t stream) {
  const float* pt_fea   = (const float*)d_in[0];
  const int*   grid_ind = (const int*)d_in[1];
  const float* occup    = (const float*)d_in[2];
  const float* W1 = (const float*)d_in[3];  const float* b1 = (const float*)d_in[4];
  const float* W2 = (const float*)d_in[5];  const float* b2 = (const float*)d_in[6];
  const float* W3 = (const float*)d_in[7];  const float* b3 = (const float*)d_in[8];
  const float* W4 = (const float*)d_in[9];  const float* b4 = (const float*)d_in[10];
  const float* g0 = (const float*)d_in[11]; const float* be0 = (const float*)d_in[12];
  const float* g1 = (const float*)d_in[13]; const float* be1 = (const float*)d_in[14];
  const float* g2 = (const float*)d_in[15]; const float* be2 = (const float*)d_in[16];
  const float* g3 = (const float*)d_in[17]; const float* be3 = (const float*)d_in[18];
  const float* Wc = (const float*)d_in[19]; const float* bc = (const float*)d_in[20];
  float* out = (float*)d_out;

  const int nPts = in_sizes[0] / 3;  // 240000
  const int perB = nPts / 2;         // 120000
  const float invN = 1.f / (float)nPts;

  // ---- workspace layout, peak ~215.4 MB ----
  char* ws = (char*)d_ws;
  float* stats = (float*)ws;
  float* scsh  = (float*)(ws + 4096);
  float* sums0 = stats;        float* sums1 = stats + 16;
  float* sums2 = stats + 160;  float* sums3 = stats + 416;
  float* sc0 = scsh;
  float* sc1 = scsh + 16;   float* sh1 = scsh + 80;
  float* sc2 = scsh + 144;  float* sh2 = scsh + 272;
  float* sc3 = scsh + 400;  float* sh3 = scsh + 656;
  __hip_bfloat16* Wt2 = (__hip_bfloat16*)(ws + 8192);     // 16 KB
  __hip_bfloat16* Wt3 = (__hip_bfloat16*)(ws + 24576);    // 64 KB
  __hip_bfloat16* Wt4 = (__hip_bfloat16*)(ws + 90112);    // 256 KB
  __hip_bfloat16* WcT = (__hip_bfloat16*)(ws + 352256);   // 32 KB -> ends 385024
  char* S0 = ws + 385024;
  __hip_bfloat16* Y1 = (__hip_bfloat16*)S0;                    // 30.72 MB
  __hip_bfloat16* Y2 = (__hip_bfloat16*)(S0 + 30720000ll);     // 61.44 MB
  __hip_bfloat16* Y3 = (__hip_bfloat16*)(S0 + 92160000ll);     // 122.88 MB
  // stage-4 aliases over dead Y1 (sort region written only AFTER stage 2 in
  // stream order; comp written only by pool_compress):
  float* comp       = (float*)S0;                              // 16.78 MB
  char* sortBase    = S0 + 17000000ll;                         // inside Y1, after comp
  unsigned* hist    = (unsigned*)sortBase;                     // 2*65536   (512 KB)
  unsigned* cursor  = hist + 2 * 65536;                        // 2*65536   (512 KB)
  unsigned* bSums   = cursor + 2 * 65536;                      // 2*256 (pad 1024)
  unsigned* startsA = bSums + 1024;                            // 2*65537 (pad 131080)
  unsigned* cells   = startsA + 131080;                        // 2*perB    (960 KB)
  unsigned* invPos  = cells + 2 * perB;                        // 2*perB    (960 KB)
  // sort region ends ~S0+20.5 MB < Y1 end (30.72 MB): never touches Y2/Y3.

  hipMemsetAsync(stats, 0, 4096, stream);

  wconv4<<<736, 256, 0, stream>>>(W2, W3, W4, Wc, Wt2, Wt3, Wt4, WcT);

  // stage 0
  stats_feats<<<256, 256, 0, stream>>>(pt_fea, nPts, sums0);
  bn_prep<<<1, 256, 0, stream>>>(sums0, 3, invN, g0, be0, sc0, scsh + 4);

  // stage 1 (fused stats)
  gemm1_stats<<<512, 256, 0, stream>>>(pt_fea, W1, b1, scsh, Y1, nPts, sums1);
  bn_prep<<<1, 256, 0, stream>>>(sums1, 64, invN, g1, be1, sc1, sh1);

  // stage 2 (MFMA, fused stats)
  gemm_mfma<64><<<dim3(nPts / 128, 1), 256, 0, stream>>>(Y1, Wt2, b2, sc1, sh1, Y2, 128, sums2, nPts, nullptr);
  bn_prep<<<1, 256, 0, stream>>>(sums2, 128, invN, g2, be2, sc2, sh2);

  // counting sort BEFORE stage 3 (needs only grid_ind; sort region aliases Y1,
  // which is dead after stage 2 -- memset must come AFTER stage-2 enqueue).
  hipMemsetAsync(hist, 0, 2 * 65536 * 4, stream);
  const int pgrid = (perB + 255) / 256;
  hist_kernel<<<dim3(pgrid, 2), 256, 0, stream>>>(grid_ind, perB, hist);
  scan1<<<dim3(256, 2), 256, 0, stream>>>(hist, cursor, bSums);
  scan2<<<2, 256, 0, stream>>>(bSums);
  mk_starts<<<dim3(256, 2), 256, 0, stream>>>(cursor, bSums, startsA, perB);
  scatter_kernel<<<dim3(pgrid, 2), 256, 0, stream>>>(grid_ind, perB, cursor, bSums, cells, invPos);

  // stage 3 (MFMA, fused stats, PERMUTED write: Y3 lands in sorted order)
  gemm_mfma<128><<<dim3(nPts / 128, 2), 256, 0, stream>>>(Y2, Wt3, b3, sc2, sh2, Y3, 256, sums3, nPts, invPos);
  bn_prep<<<1, 256, 0, stream>>>(sums3, 256, invN, g3, be3, sc3, sh3);

  // fused stage-4: pool + compress, contiguous Y3 reads, run-merged atomics.
  // 32 cells/block -> (2048, 2).
  pool_compress<<<dim3(2048, 2), 256, 0, stream>>>(
      Y3, Wt4, b4, sc3, sh3, WcT, bc, cells, startsA, comp, perB);

  // fused epilogue: separable maxpool (2048 blocks) + occupancy transpose (4096 blocks)
  epilogue_write<<<6144, 256, 0, stream>>>(comp, occup, out);
}